// Round 6
// baseline (3385.736 us; speedup 1.0000x reference)
//
#include <hip/hip_runtime.h>

// =====================================================================
// DecoderLayer: selfMHA -> LN -> crossMHA -> LN -> 32xLSTM(pipelined)
//               -> pointwise conv -> LN
// Round 15: remove DS ops from the LSTM recurrence. R9-R13 pin the
//   per-step cost at ~1.38k cyc, invariant to schedule/occupancy; the
//   step's critical path crosses the in-order DS queue 4x (h LDS
//   write, 13 h2v reads, 2 shuffles). New dataflow: h stays in regs,
//   broadcast via 25 v_readlane -> 13 uniform packed h2v (SALU), fdot2
//   reads them directly; only 2 shfl_xor(32) DS ops remain per step.
//   Lane map: lane u<25 rows {i_u,g_u}, lane 32+u rows {f_u,o_u},
//   branch-free, both halves compute c,h redundantly. Grid/protocol =
//   R13 (1024 blocks, lag-1 handoff) byte-for-byte.
// =====================================================================

#define EPS_LN 1e-5f

typedef _Float16 h2v __attribute__((ext_vector_type(2)));
typedef _Float16 h8v __attribute__((ext_vector_type(8)));
typedef float    f4v __attribute__((ext_vector_type(4)));

#if defined(__has_builtin)
#if __has_builtin(__builtin_amdgcn_fdot2)
#define HAVE_FDOT2 1
#endif
#if __has_builtin(__builtin_amdgcn_rcpf)
#define HAVE_RCPF 1
#endif
#endif

__device__ __forceinline__ float fdot2(h2v a, h2v b, float c) {
#ifdef HAVE_FDOT2
  return __builtin_amdgcn_fdot2(a, b, c, false);
#else
  return c + (float)a.x * (float)b.x + (float)a.y * (float)b.y;
#endif
}
__device__ __forceinline__ h2v bch2(unsigned int u) {
  return __builtin_bit_cast(h2v, u);
}
__device__ __forceinline__ float rcp_fast(float x) {
#ifdef HAVE_RCPF
  return __builtin_amdgcn_rcpf(x);
#else
  return 1.f / x;
#endif
}
__device__ __forceinline__ float sigm_fast(float x) {
  return rcp_fast(1.f + __expf(-x));
}
__device__ __forceinline__ float tanh_fast(float x) {
  return 1.f - 2.f * rcp_fast(1.f + __expf(2.f * x));
}

// ---------------- fused weight prep: 8 transposes + 1 straight cvt -------
struct WPtrs { const float* p[9]; };

__global__ __launch_bounds__(256)
void prep_weights(WPtrs w, _Float16* __restrict__ dst) {
  __shared__ float tile[32][33];
  const int z = blockIdx.z;
  const int tx = threadIdx.x & 31, ty = threadIdx.x >> 5;
  const int bx = blockIdx.x, by = blockIdx.y;
  const float* in = w.p[z];
  _Float16* outp = dst + (size_t)z * 262144;
  if (z < 8) {
#pragma unroll
    for (int i = 0; i < 4; i++)
      tile[ty + i * 8][tx] = in[(size_t)(by * 32 + ty + i * 8) * 512 + bx * 32 + tx];
    __syncthreads();
#pragma unroll
    for (int i = 0; i < 4; i++)
      outp[(size_t)(bx * 32 + ty + i * 8) * 512 + by * 32 + tx] = (_Float16)tile[tx][ty + i * 8];
  } else {
#pragma unroll
    for (int i = 0; i < 4; i++) {
      size_t off = (size_t)(by * 32 + ty + i * 8) * 512 + bx * 32 + tx;
      outp[off] = (_Float16)in[off];
    }
  }
}

// ---------------- f16 MFMA GEMM, fp32 A staged+converted in LDS ----------
__global__ __launch_bounds__(256)
void gemm3(const float* __restrict__ A,
           const _Float16* __restrict__ BT0, const _Float16* __restrict__ BT1,
           const _Float16* __restrict__ BT2,
           const float* __restrict__ bias0, const float* __restrict__ bias1,
           const float* __restrict__ bias2,
           float* __restrict__ C0, float* __restrict__ C1, float* __restrict__ C2,
           int M) {
  __shared__ _Float16 Asld[64 * 40];
  __shared__ _Float16 Bsld[64 * 40];
  const int t = threadIdx.x;
  const int which = blockIdx.x >> 3;
  const int n0 = (blockIdx.x & 7) * 64;
  const int m0 = blockIdx.y * 64;
  const _Float16* BT = (which == 0) ? BT0 : (which == 1) ? BT1 : BT2;
  const float* bias  = (which == 0) ? bias0 : (which == 1) ? bias1 : bias2;
  float* C           = (which == 0) ? C0 : (which == 1) ? C1 : C2;

  const int r = t >> 2, q = t & 3;
  const int w = t >> 6;
  const int lane = t & 63;
  const int lm = lane & 15, q8 = lane >> 4;

  f4v acc[4] = {};
  for (int k0 = 0; k0 < 512; k0 += 32) {
    __syncthreads();
    float4 f0 = *(const float4*)&A[(size_t)(m0 + r) * 512 + k0 + q * 8];
    float4 f1 = *(const float4*)&A[(size_t)(m0 + r) * 512 + k0 + q * 8 + 4];
    h8v hvv = {(_Float16)f0.x, (_Float16)f0.y, (_Float16)f0.z, (_Float16)f0.w,
               (_Float16)f1.x, (_Float16)f1.y, (_Float16)f1.z, (_Float16)f1.w};
    *(h8v*)&Asld[r * 40 + q * 8] = hvv;
    *(uint4*)&Bsld[r * 40 + q * 8] = *(const uint4*)&BT[(size_t)(n0 + r) * 512 + k0 + q * 8];
    __syncthreads();
    h8v a = *(const h8v*)&Asld[(w * 16 + lm) * 40 + q8 * 8];
#pragma unroll
    for (int nt = 0; nt < 4; nt++) {
      h8v b = *(const h8v*)&Bsld[(nt * 16 + lm) * 40 + q8 * 8];
      acc[nt] = __builtin_amdgcn_mfma_f32_16x16x32_f16(a, b, acc[nt], 0, 0, 0);
    }
  }
#pragma unroll
  for (int nt = 0; nt < 4; nt++) {
    int gn = n0 + nt * 16 + lm;
    float bv = bias[gn];
#pragma unroll
    for (int rg = 0; rg < 4; rg++) {
      int gm = m0 + w * 16 + q8 * 4 + rg;
      C[(size_t)gm * 512 + gn] = acc[nt][rg] + bv;
    }
  }
}

// ---------------- attention: scores then softmax+PV, per (b,h) -----------
template <int S>
__global__ __launch_bounds__(256)
void attn_scores(const float* __restrict__ Q, const float* __restrict__ K,
                 float* __restrict__ P) {
  __shared__ float Qs[25][64];
  __shared__ float Ks[S][65];
  const int h = blockIdx.x, b = blockIdx.y, t = threadIdx.x;
  for (int idx = t; idx < 25 * 64; idx += 256) {
    int l = idx >> 6, e = idx & 63;
    Qs[l][e] = Q[(b * 25 + l) * 512 + h * 64 + e];
  }
  for (int idx = t; idx < S * 64; idx += 256) {
    int s = idx >> 6, e = idx & 63;
    Ks[s][e] = K[(b * S + s) * 512 + h * 64 + e];
  }
  __syncthreads();
  float* Pb = P + (size_t)(b * 8 + h) * 25 * S;
  for (int idx = t; idx < 25 * S; idx += 256) {
    int l = idx / S, s = idx % S;
    float acc = 0.f;
#pragma unroll
    for (int e = 0; e < 64; e++) acc += Qs[l][e] * Ks[s][e];
    Pb[idx] = acc * 0.125f;
  }
}

template <int S>
__global__ __launch_bounds__(256)
void attn_out(const float* __restrict__ P, const float* __restrict__ V,
              float* __restrict__ O) {
  __shared__ float Ps[25][S];
  __shared__ float Vs[S][64];
  const int h = blockIdx.x, b = blockIdx.y, t = threadIdx.x;
  const float* Pb = P + (size_t)(b * 8 + h) * 25 * S;
  for (int idx = t; idx < 25 * S; idx += 256) Ps[idx / S][idx % S] = Pb[idx];
  for (int idx = t; idx < S * 64; idx += 256) {
    int s = idx >> 6, e = idx & 63;
    Vs[s][e] = V[(b * S + s) * 512 + h * 64 + e];
  }
  __syncthreads();
  if (t < 25) {
    float mx = -1e30f;
    for (int s = 0; s < S; s++) mx = fmaxf(mx, Ps[t][s]);
    float sum = 0.f;
    for (int s = 0; s < S; s++) { float p = __expf(Ps[t][s] - mx); Ps[t][s] = p; sum += p; }
    float r = 1.f / sum;
    for (int s = 0; s < S; s++) Ps[t][s] *= r;
  }
  __syncthreads();
  for (int idx = t; idx < 25 * 64; idx += 256) {
    int l = idx >> 6, e = idx & 63;
    float acc = 0.f;
    for (int s = 0; s < S; s++) acc += Ps[l][s] * Vs[s][e];
    O[(b * 25 + l) * 512 + h * 64 + e] = acc;
  }
}

// ---------------- fused residual-add + LayerNorm (rows of 512) -----------
__global__ __launch_bounds__(128)
void add_ln(const float* __restrict__ a, const float* __restrict__ b,
            const float* __restrict__ gw, const float* __restrict__ bw,
            float* __restrict__ out) {
  const int row = blockIdx.x, t = threadIdx.x;
  float4 va = ((const float4*)(a + (size_t)row * 512))[t];
  float4 vb = ((const float4*)(b + (size_t)row * 512))[t];
  float4 v = make_float4(va.x + vb.x, va.y + vb.y, va.z + vb.z, va.w + vb.w);
  float s = v.x + v.y + v.z + v.w;
  float q = v.x * v.x + v.y * v.y + v.z * v.z + v.w * v.w;
#pragma unroll
  for (int off = 32; off > 0; off >>= 1) {
    s += __shfl_down(s, off);
    q += __shfl_down(q, off);
  }
  __shared__ float red[4];
  if ((t & 63) == 0) { red[(t >> 6) * 2] = s; red[(t >> 6) * 2 + 1] = q; }
  __syncthreads();
  float S_ = red[0] + red[2], Q_ = red[1] + red[3];
  float mean = S_ * (1.f / 512.f);
  float var  = Q_ * (1.f / 512.f) - mean * mean;
  float inv  = rsqrtf(var + EPS_LN);
  float4 g4 = ((const float4*)gw)[t];
  float4 b4 = ((const float4*)bw)[t];
  float4 o;
  o.x = (v.x - mean) * inv * g4.x + b4.x;
  o.y = (v.y - mean) * inv * g4.y + b4.y;
  o.z = (v.z - mean) * inv * g4.z + b4.z;
  o.w = (v.w - mean) * inv * g4.w + b4.w;
  ((float4*)(out + (size_t)row * 512))[t] = o;
}

// ---------------- transposes / LSTM preps --------------------------------
__global__ void transpose_dl(const float* __restrict__ in, float* __restrict__ outp) {
  const int b = blockIdx.x, t = threadIdx.x;
  for (int idx = t; idx < 25 * 512; idx += 256) {
    int l2 = idx / 512, c = idx % 512;
    outp[((size_t)b * 25 + l2) * 512 + c] = in[((size_t)b * 512 + c) * 25 + l2];
  }
}

// X0[b][t=512][32] f16 from x2[b][25][512] (u>=25 pads = 0)
__global__ __launch_bounds__(256)
void prep_x0r(const float* __restrict__ x2, _Float16* __restrict__ X0) {
  __shared__ float tile[25][516];
  const int b = blockIdx.x, t = threadIdx.x;
  for (int idx = t; idx < 25 * 512; idx += 256) {
    int u = idx >> 9, d = idx & 511;
    tile[u][d] = x2[((size_t)b * 25 + u) * 512 + d];
  }
  __syncthreads();
  for (int idx = t; idx < 512 * 32; idx += 256) {
    int d = idx >> 5, u = idx & 31;
    X0[((size_t)b * 512 + d) * 32 + u] = (u < 25) ? (_Float16)tile[u][d] : (_Float16)0.f;
  }
}

// ---------------- pipelined 32-layer LSTM (fdot2, wave-autonomous) -------
// R15: 1024 blocks (32 layers x 32 groups of 4 batches), 256 thr.
// ONE batch per 64-lane wave; lane u<25 rows {i_u,g_u}, lane 32+u rows
// {f_u,o_u}; h lives in registers (readlane broadcast), no hbuf.
// R13 lag-1 handoff protocol unchanged.
#define NLAY 32
#define NGRP 32
#define BGRP 4
#define CHT  8
#define NCHK 64
#define RSLOTS 64
#define RCHK (RSLOTS / CHT)
#define RLAY ((size_t)128 * RSLOTS * 32)   // halves per layer region

__device__ __forceinline__ int ld_rlx(int* p) {
  return __hip_atomic_load(p, __ATOMIC_RELAXED, __HIP_MEMORY_SCOPE_AGENT);
}
__device__ __forceinline__ void st_rlx(int* p, int v) {
  __hip_atomic_store(p, v, __ATOMIC_RELAXED, __HIP_MEMORY_SCOPE_AGENT);
}
__device__ __forceinline__ unsigned long long ldq_rlx(const unsigned long long* p) {
  return __hip_atomic_load(p, __ATOMIC_RELAXED, __HIP_MEMORY_SCOPE_AGENT);
}
__device__ __forceinline__ void sth_rlx(_Float16* p, _Float16 v) {
  __hip_atomic_store((unsigned short*)p, __builtin_bit_cast(unsigned short, v),
                     __ATOMIC_RELAXED, __HIP_MEMORY_SCOPE_AGENT);
}

__global__ __launch_bounds__(256) __attribute__((amdgpu_waves_per_eu(4, 4)))
void lstm_pipeline(const _Float16* __restrict__ X0, float* __restrict__ yout,
                   _Float16* __restrict__ ring, int* __restrict__ prod,
                   int* __restrict__ cons,
                   const float* __restrict__ Wih, const float* __restrict__ Whh,
                   const float* __restrict__ bih, const float* __restrict__ bhh) {
  const int l = blockIdx.x / NGRP;
  const int g = blockIdx.x % NGRP;
  const int t = threadIdx.x;
  const int lane = t & 63;
  const int wv   = t >> 6;               // batch slot in block, 0..3
  const bool lo  = (lane < 32);          // low half: rows {i,g}; hi: {f,o}

  __shared__ _Float16 xbuf[CHT][BGRP][32];  // chunk input (2 KB)

  // ---- weights packed half2: lane u<32 rows {u,u+50}; lane 32+u rows
  //      {25+u, 75+u}  (u clamped to 24 for junk lanes) ----
  h2v wih2[2][13], whh2[2][13];
  float bias_r[2];
  float c_reg = 0.f;
  h2v hk[13];
#pragma unroll
  for (int k = 0; k < 13; k++) hk[k] = h2v{(_Float16)0.f, (_Float16)0.f};
  {
    const int uu = ((lane & 31) < 25) ? (lane & 31) : 24;
    const int r0 = uu + (lane >> 5) * 25;   // i-row | f-row
#pragma unroll
    for (int j = 0; j < 2; j++) {
      const int row = r0 + j * 50;          // {i,g} | {f,o}
      const float* wi = &Wih[((size_t)l * 100 + row) * 25];
      const float* wh = &Whh[((size_t)l * 100 + row) * 25];
#pragma unroll
      for (int k = 0; k < 13; k++) {
        float alo = wi[2 * k], ahi = (2 * k + 1 < 25) ? wi[2 * k + 1] : 0.f;
        float blo = wh[2 * k], bhi = (2 * k + 1 < 25) ? wh[2 * k + 1] : 0.f;
        wih2[j][k] = h2v{(_Float16)alo, (_Float16)ahi};
        whh2[j][k] = h2v{(_Float16)blo, (_Float16)bhi};
      }
      bias_r[j] = bih[l * 100 + row] + bhh[l * 100 + row];
    }
  }
  __syncthreads();

  // producer out pointers
  const int bglob = g * BGRP + wv;
  _Float16* ring_out = ring + (size_t)l * RLAY
                       + ((size_t)bglob * RSLOTS) * 32 + lane;
  float* yout_out = yout + ((size_t)bglob * 512) * 25 + lane;

  // staging mapping: thread -> (tc, batch, 8B segment); 8B per thread
  const int s_tc = t >> 5, s_b2 = (t >> 3) & 3, s_seg = t & 7;

  int* prod_in   = prod + (l - 1) * NGRP + g;   // valid only when l > 0
  int* prod_out  = prod + l * NGRP + g;         // valid only when l < NLAY-1
  int* cons_self = cons + l * NGRP + g;         // valid only when l > 0
  int* cons_up   = cons + (l + 1) * NGRP + g;   // valid only when l < NLAY-1

  for (int n = 0; n < NCHK; n++) {
    if (t == 0) {
      if (l > 0) {
        while (ld_rlx(prod_in) < n + 1) __builtin_amdgcn_s_sleep(1);
      }
      if (l < NLAY - 1 && n >= RCHK) {
        while (ld_rlx(cons_up) < n - RCHK + 1) __builtin_amdgcn_s_sleep(1);
      }
    }
    __syncthreads();                                   // (A) poll done
    // ---- stage chunk: ONE 8B load per thread ----
    {
      const int tg = n * CHT + s_tc;
      if (l == 0) {
        unsigned long long a = *(const unsigned long long*)(X0
            + (((size_t)(g * BGRP + s_b2) * 512) + tg) * 32 + s_seg * 4);
        *(unsigned long long*)&xbuf[s_tc][s_b2][s_seg * 4] = a;
      } else {
        const unsigned long long* p = (const unsigned long long*)(ring
            + (size_t)(l - 1) * RLAY
            + (((size_t)(g * BGRP + s_b2) * RSLOTS) + (tg & (RSLOTS - 1))) * 32
            + s_seg * 4);
        unsigned long long a = ldq_rlx(p);
        *(unsigned long long*)&xbuf[s_tc][s_b2][s_seg * 4] = a;
      }
    }
    __syncthreads();                                   // (B) staging visible
    if (t == 0 && l > 0) st_rlx(cons_self, n + 1);

    // ---- x-part for all 8 steps: dense, branch-free ----
    float ax[CHT][2];
#pragma unroll
    for (int tc = 0; tc < CHT; tc++) {
      const unsigned int* xr = (const unsigned int*)&xbuf[tc][wv][0];
      uint4 xa = *(const uint4*)(xr);
      uint4 xb = *(const uint4*)(xr + 4);
      uint4 xc = *(const uint4*)(xr + 8);
      unsigned int xd = xr[12];
      h2v xk[13] = {bch2(xa.x), bch2(xa.y), bch2(xa.z), bch2(xa.w),
                    bch2(xb.x), bch2(xb.y), bch2(xb.z), bch2(xb.w),
                    bch2(xc.x), bch2(xc.y), bch2(xc.z), bch2(xc.w),
                    bch2(xd)};
      float a0 = bias_r[0], a1 = bias_r[1];
#pragma unroll
      for (int k = 0; k < 13; k++) {
        a0 = fdot2(wih2[0][k], xk[k], a0);
        a1 = fdot2(wih2[1][k], xk[k], a1);
      }
      ax[tc][0] = a0; ax[tc][1] = a1;
    }

    // ---- serial h-recurrence: 8 steps; h in regs, no LDS ----
#pragma unroll
    for (int tc = 0; tc < CHT; tc++) {
      const int tg = n * CHT + tc;
      float a0 = ax[tc][0], a1 = ax[tc][1];
#pragma unroll
      for (int k = 0; k < 13; k++) {
        a0 = fdot2(whh2[0][k], hk[k], a0);
        a1 = fdot2(whh2[1][k], hk[k], a1);
      }
      // lo lane u: a0=i_u, a1=g_u.  hi lane 32+u: a0=f_u, a1=o_u.
      float p0 = sigm_fast(a0);                  // sigma(i) | sigma(f)
      float p1 = lo ? tanh_fast(a1) : sigm_fast(a1);  // tanh(g) | sigma(o)
      float q0 = __shfl_xor(p0, 32, 64);
      float q1 = __shfl_xor(p1, 32, 64);
      float si  = lo ? p0 : q0;
      float sf  = lo ? q0 : p0;
      float tg_ = lo ? p1 : q1;
      float so  = lo ? q1 : p1;
      c_reg = sf * c_reg + si * tg_;
      float h = so * tanh_fast(c_reg);
      _Float16 h16 = (_Float16)h;
      unsigned hu = (unsigned)__builtin_bit_cast(unsigned short, h16);
      if (lane < 25) {
        if (l == NLAY - 1)
          yout_out[(size_t)tg * 25] = h;
        else
          sth_rlx(ring_out + (size_t)(tg & (RSLOTS - 1)) * 32, h16);
      }
      // broadcast h -> 13 uniform packed h2v for the next step (no LDS)
#pragma unroll
      for (int k = 0; k < 13; k++) {
        unsigned lo16 = ((unsigned)__builtin_amdgcn_readlane((int)hu, 2 * k)) & 0xffffu;
        unsigned hi16 = (2 * k + 1 < 25)
            ? (((unsigned)__builtin_amdgcn_readlane((int)hu, 2 * k + 1)) << 16)
            : 0u;
        hk[k] = bch2(lo16 | hi16);
      }
    }
    asm volatile("s_waitcnt vmcnt(0)" ::: "memory");   // ring stores at MALL
    __syncthreads();                                   // (C) all waves done
    if (t == 0 && l < NLAY - 1) st_rlx(prod_out, n + 1);
  }
}

// =====================================================================
extern "C" void kernel_launch(void* const* d_in, const int* in_sizes, int n_in,
                              void* d_out, int out_size, void* d_ws, size_t ws_size,
                              hipStream_t stream) {
  const float* x     = (const float*)d_in[0];
  const float* cross = (const float*)d_in[1];
  const float* Wq_s = (const float*)d_in[2];  const float* bq_s = (const float*)d_in[3];
  const float* Wk_s = (const float*)d_in[4];  const float* bk_s = (const float*)d_in[5];
  const float* Wv_s = (const float*)d_in[6];  const float* bv_s = (const float*)d_in[7];
  const float* Wo_s = (const float*)d_in[8];  const float* bo_s = (const float*)d_in[9];
  const float* Wq_c = (const float*)d_in[10]; const float* bq_c = (const float*)d_in[11];
  const float* Wk_c = (const float*)d_in[12]; const float* bk_c = (const float*)d_in[13];
  const float* Wv_c = (const float*)d_in[14]; const float* bv_c = (const float*)d_in[15];
  const float* Wo_c = (const float*)d_in[16]; const float* bo_c = (const float*)d_in[17];
  const float* g1 = (const float*)d_in[18]; const float* b1 = (const float*)d_in[19];
  const float* g2 = (const float*)d_in[20]; const float* b2 = (const float*)d_in[21];
  const float* g3 = (const float*)d_in[22]; const float* b3 = (const float*)d_in[23];
  const float* Wih = (const float*)d_in[24];
  const float* Whh = (const float*)d_in[25];
  const float* bih = (const float*)d_in[26];
  const float* bhh = (const float*)d_in[27];
  const float* Wc  = (const float*)d_in[28]; const float* bc = (const float*)d_in[29];
  float* out = (float*)d_out;
  float* ws  = (float*)d_ws;

  // ---- workspace (floats); time-multiplexed regions ---------------------
  constexpr size_t A  = 1638400;    // 3200*512
  constexpr size_t C6 = 6291456;    // 12288*512
  float* x1    = ws;
  float* Qc    = ws + A;
  // self phase
  float* Qs    = ws + 2 * A;
  float* Ks    = ws + 3 * A;
  float* Vs    = ws + 4 * A;
  float* attns = ws + 5 * A;
  float* tmp   = ws + 6 * A;
  float* Ps    = ws + 7 * A;
  // cross phase
  float* Kc    = ws + 2 * A;
  float* Vc    = ws + 2 * A + C6;
  float* attnc = ws + 2 * A + 2 * C6;
  float* Pc    = attnc + A;
  float* tmp2  = ws + 6 * A;
  float* x2    = ws + 3 * A;
  // lstm / post
  _Float16* X0b  = (_Float16*)(ws + 4 * A);      // 128*512*32 halves = 1.05M fl
  float*    youtb = ws + 5 * A;                  // [128][512][25] fp32
  _Float16* ringb = (_Float16*)(ws + 6 * A);     // 31*RLAY = 8.13M halves
  float* ytb   = ws + 2 * A;
  float* fy    = ws + 5 * A;                     // after youtb dead
  _Float16* WTall = (_Float16*)(ws + 20000000);
  int* ctr = (int*)(ws + 21179648);

  dim3 blk(256);
  WPtrs wpq;
  wpq.p[0] = Wq_s; wpq.p[1] = Wk_s; wpq.p[2] = Wv_s; wpq.p[3] = Wo_s;
  wpq.p[4] = Wq_c; wpq.p[5] = Wk_c; wpq.p[6] = Wv_c; wpq.p[7] = Wo_c;
  wpq.p[8] = Wc;
  prep_weights<<<dim3(16, 16, 9), blk, 0, stream>>>(wpq, WTall);
  hipMemsetAsync(ctr, 0, 2048 * sizeof(int), stream);
  _Float16* WT[9];
  for (int i = 0; i < 9; i++) WT[i] = WTall + (size_t)i * 262144;

  // ---- self attention ----
  gemm3<<<dim3(24, 50), blk, 0, stream>>>(x, WT[0], WT[1], WT[2],
                                          bq_s, bk_s, bv_s, Qs, Ks, Vs, 3200);
  attn_scores<25><<<dim3(8, 128), blk, 0, stream>>>(Qs, Ks, Ps);
  attn_out<25><<<dim3(8, 128), blk, 0, stream>>>(Ps, Vs, attns);
  gemm3<<<dim3(8, 50), blk, 0, stream>>>(attns, WT[3], WT[3], WT[3],
                                         bo_s, bo_s, bo_s, tmp, tmp, tmp, 3200);
  add_ln<<<3200, 128, 0, stream>>>(x, tmp, g1, b1, x1);
  // ---- cross attention ----
  gemm3<<<dim3(8, 50), blk, 0, stream>>>(x1, WT[4], WT[4], WT[4],
                                         bq_c, bq_c, bq_c, Qc, Qc, Qc, 3200);
  gemm3<<<dim3(16, 192), blk, 0, stream>>>(cross, WT[5], WT[6], WT[6],
                                           bk_c, bv_c, bv_c, Kc, Vc, Vc, 12288);
  attn_scores<96><<<dim3(8, 128), blk, 0, stream>>>(Qc, Kc, Pc);
  attn_out<96><<<dim3(8, 128), blk, 0, stream>>>(Pc, Vc, attnc);
  gemm3<<<dim3(8, 50), blk, 0, stream>>>(attnc, WT[7], WT[7], WT[7],
                                         bo_c, bo_c, bo_c, tmp2, tmp2, tmp2, 3200);
  add_ln<<<3200, 128, 0, stream>>>(x1, tmp2, g2, b2, x2);
  // ---- LSTM over feature axis ----
  prep_x0r<<<128, 256, 0, stream>>>(x2, X0b);
  lstm_pipeline<<<NLAY * NGRP, 256, 0, stream>>>(X0b, youtb, ringb, ctr, ctr + 1024,
                                                 Wih, Whh, bih, bhh);
  // ---- pointwise conv over channels + final LN ----
  transpose_dl<<<128, 256, 0, stream>>>(youtb, ytb);
  gemm3<<<dim3(8, 50), blk, 0, stream>>>(ytb, WT[8], WT[8], WT[8],
                                         bc, bc, bc, fy, fy, fy, 3200);
  add_ln<<<3200, 128, 0, stream>>>(x2, fy, g3, b3, out);
}

// Round 7
// 932.520 us; speedup vs baseline: 3.6307x; 3.6307x over previous
//
#include <hip/hip_runtime.h>

// =====================================================================
// DecoderLayer: selfMHA -> LN -> crossMHA -> LN -> 32xLSTM(pipelined)
//               -> pointwise conv -> LN
// Round 16: REVERT to the verified R9 structure (715us lstm, 1039-1045us
//   total) after R10-R15 established its period is invariant to lag,
//   chunk size, overlap, occupancy, dual-chain ILP, and reg-resident h
//   (the last two regressed badly). Single isolated change kept: the 5
//   exact divisions per LSTM step (3 sigmoid + 2 tanh) use v_rcp_f32
//   (~1 ulp; R14/R15 showed absmax unchanged) instead of rcp+Newton.
// =====================================================================

#define EPS_LN 1e-5f

typedef _Float16 h2v __attribute__((ext_vector_type(2)));
typedef _Float16 h8v __attribute__((ext_vector_type(8)));
typedef float    f4v __attribute__((ext_vector_type(4)));

#if defined(__has_builtin)
#if __has_builtin(__builtin_amdgcn_fdot2)
#define HAVE_FDOT2 1
#endif
#if __has_builtin(__builtin_amdgcn_rcpf)
#define HAVE_RCPF 1
#endif
#endif

__device__ __forceinline__ float fdot2(h2v a, h2v b, float c) {
#ifdef HAVE_FDOT2
  return __builtin_amdgcn_fdot2(a, b, c, false);
#else
  return c + (float)a.x * (float)b.x + (float)a.y * (float)b.y;
#endif
}
__device__ __forceinline__ h2v bch2(unsigned int u) {
  return __builtin_bit_cast(h2v, u);
}
__device__ __forceinline__ float rcp_fast(float x) {
#ifdef HAVE_RCPF
  return __builtin_amdgcn_rcpf(x);
#else
  return 1.f / x;
#endif
}
__device__ __forceinline__ float sigm_fast(float x) {
  return rcp_fast(1.f + __expf(-x));
}
__device__ __forceinline__ float tanh_fast(float x) {
  return 1.f - 2.f * rcp_fast(1.f + __expf(2.f * x));
}

// ---------------- fused weight prep: 8 transposes + 1 straight cvt -------
struct WPtrs { const float* p[9]; };

__global__ __launch_bounds__(256)
void prep_weights(WPtrs w, _Float16* __restrict__ dst) {
  __shared__ float tile[32][33];
  const int z = blockIdx.z;
  const int tx = threadIdx.x & 31, ty = threadIdx.x >> 5;
  const int bx = blockIdx.x, by = blockIdx.y;
  const float* in = w.p[z];
  _Float16* outp = dst + (size_t)z * 262144;
  if (z < 8) {
#pragma unroll
    for (int i = 0; i < 4; i++)
      tile[ty + i * 8][tx] = in[(size_t)(by * 32 + ty + i * 8) * 512 + bx * 32 + tx];
    __syncthreads();
#pragma unroll
    for (int i = 0; i < 4; i++)
      outp[(size_t)(bx * 32 + ty + i * 8) * 512 + by * 32 + tx] = (_Float16)tile[tx][ty + i * 8];
  } else {
#pragma unroll
    for (int i = 0; i < 4; i++) {
      size_t off = (size_t)(by * 32 + ty + i * 8) * 512 + bx * 32 + tx;
      outp[off] = (_Float16)in[off];
    }
  }
}

// ---------------- f16 MFMA GEMM, fp32 A staged+converted in LDS ----------
__global__ __launch_bounds__(256)
void gemm3(const float* __restrict__ A,
           const _Float16* __restrict__ BT0, const _Float16* __restrict__ BT1,
           const _Float16* __restrict__ BT2,
           const float* __restrict__ bias0, const float* __restrict__ bias1,
           const float* __restrict__ bias2,
           float* __restrict__ C0, float* __restrict__ C1, float* __restrict__ C2,
           int M) {
  __shared__ _Float16 Asld[64 * 40];
  __shared__ _Float16 Bsld[64 * 40];
  const int t = threadIdx.x;
  const int which = blockIdx.x >> 3;
  const int n0 = (blockIdx.x & 7) * 64;
  const int m0 = blockIdx.y * 64;
  const _Float16* BT = (which == 0) ? BT0 : (which == 1) ? BT1 : BT2;
  const float* bias  = (which == 0) ? bias0 : (which == 1) ? bias1 : bias2;
  float* C           = (which == 0) ? C0 : (which == 1) ? C1 : C2;

  const int r = t >> 2, q = t & 3;
  const int w = t >> 6;
  const int lane = t & 63;
  const int lm = lane & 15, q8 = lane >> 4;

  f4v acc[4] = {};
  for (int k0 = 0; k0 < 512; k0 += 32) {
    __syncthreads();
    float4 f0 = *(const float4*)&A[(size_t)(m0 + r) * 512 + k0 + q * 8];
    float4 f1 = *(const float4*)&A[(size_t)(m0 + r) * 512 + k0 + q * 8 + 4];
    h8v hvv = {(_Float16)f0.x, (_Float16)f0.y, (_Float16)f0.z, (_Float16)f0.w,
               (_Float16)f1.x, (_Float16)f1.y, (_Float16)f1.z, (_Float16)f1.w};
    *(h8v*)&Asld[r * 40 + q * 8] = hvv;
    *(uint4*)&Bsld[r * 40 + q * 8] = *(const uint4*)&BT[(size_t)(n0 + r) * 512 + k0 + q * 8];
    __syncthreads();
    h8v a = *(const h8v*)&Asld[(w * 16 + lm) * 40 + q8 * 8];
#pragma unroll
    for (int nt = 0; nt < 4; nt++) {
      h8v b = *(const h8v*)&Bsld[(nt * 16 + lm) * 40 + q8 * 8];
      acc[nt] = __builtin_amdgcn_mfma_f32_16x16x32_f16(a, b, acc[nt], 0, 0, 0);
    }
  }
#pragma unroll
  for (int nt = 0; nt < 4; nt++) {
    int gn = n0 + nt * 16 + lm;
    float bv = bias[gn];
#pragma unroll
    for (int rg = 0; rg < 4; rg++) {
      int gm = m0 + w * 16 + q8 * 4 + rg;
      C[(size_t)gm * 512 + gn] = acc[nt][rg] + bv;
    }
  }
}

// ---------------- attention: scores then softmax+PV, per (b,h) -----------
template <int S>
__global__ __launch_bounds__(256)
void attn_scores(const float* __restrict__ Q, const float* __restrict__ K,
                 float* __restrict__ P) {
  __shared__ float Qs[25][64];
  __shared__ float Ks[S][65];
  const int h = blockIdx.x, b = blockIdx.y, t = threadIdx.x;
  for (int idx = t; idx < 25 * 64; idx += 256) {
    int l = idx >> 6, e = idx & 63;
    Qs[l][e] = Q[(b * 25 + l) * 512 + h * 64 + e];
  }
  for (int idx = t; idx < S * 64; idx += 256) {
    int s = idx >> 6, e = idx & 63;
    Ks[s][e] = K[(b * S + s) * 512 + h * 64 + e];
  }
  __syncthreads();
  float* Pb = P + (size_t)(b * 8 + h) * 25 * S;
  for (int idx = t; idx < 25 * S; idx += 256) {
    int l = idx / S, s = idx % S;
    float acc = 0.f;
#pragma unroll
    for (int e = 0; e < 64; e++) acc += Qs[l][e] * Ks[s][e];
    Pb[idx] = acc * 0.125f;
  }
}

template <int S>
__global__ __launch_bounds__(256)
void attn_out(const float* __restrict__ P, const float* __restrict__ V,
              float* __restrict__ O) {
  __shared__ float Ps[25][S];
  __shared__ float Vs[S][64];
  const int h = blockIdx.x, b = blockIdx.y, t = threadIdx.x;
  const float* Pb = P + (size_t)(b * 8 + h) * 25 * S;
  for (int idx = t; idx < 25 * S; idx += 256) Ps[idx / S][idx % S] = Pb[idx];
  for (int idx = t; idx < S * 64; idx += 256) {
    int s = idx >> 6, e = idx & 63;
    Vs[s][e] = V[(b * S + s) * 512 + h * 64 + e];
  }
  __syncthreads();
  if (t < 25) {
    float mx = -1e30f;
    for (int s = 0; s < S; s++) mx = fmaxf(mx, Ps[t][s]);
    float sum = 0.f;
    for (int s = 0; s < S; s++) { float p = __expf(Ps[t][s] - mx); Ps[t][s] = p; sum += p; }
    float r = 1.f / sum;
    for (int s = 0; s < S; s++) Ps[t][s] *= r;
  }
  __syncthreads();
  for (int idx = t; idx < 25 * 64; idx += 256) {
    int l = idx >> 6, e = idx & 63;
    float acc = 0.f;
    for (int s = 0; s < S; s++) acc += Ps[l][s] * Vs[s][e];
    O[(b * 25 + l) * 512 + h * 64 + e] = acc;
  }
}

// ---------------- fused residual-add + LayerNorm (rows of 512) -----------
__global__ __launch_bounds__(128)
void add_ln(const float* __restrict__ a, const float* __restrict__ b,
            const float* __restrict__ gw, const float* __restrict__ bw,
            float* __restrict__ out) {
  const int row = blockIdx.x, t = threadIdx.x;
  float4 va = ((const float4*)(a + (size_t)row * 512))[t];
  float4 vb = ((const float4*)(b + (size_t)row * 512))[t];
  float4 v = make_float4(va.x + vb.x, va.y + vb.y, va.z + vb.z, va.w + vb.w);
  float s = v.x + v.y + v.z + v.w;
  float q = v.x * v.x + v.y * v.y + v.z * v.z + v.w * v.w;
#pragma unroll
  for (int off = 32; off > 0; off >>= 1) {
    s += __shfl_down(s, off);
    q += __shfl_down(q, off);
  }
  __shared__ float red[4];
  if ((t & 63) == 0) { red[(t >> 6) * 2] = s; red[(t >> 6) * 2 + 1] = q; }
  __syncthreads();
  float S_ = red[0] + red[2], Q_ = red[1] + red[3];
  float mean = S_ * (1.f / 512.f);
  float var  = Q_ * (1.f / 512.f) - mean * mean;
  float inv  = rsqrtf(var + EPS_LN);
  float4 g4 = ((const float4*)gw)[t];
  float4 b4 = ((const float4*)bw)[t];
  float4 o;
  o.x = (v.x - mean) * inv * g4.x + b4.x;
  o.y = (v.y - mean) * inv * g4.y + b4.y;
  o.z = (v.z - mean) * inv * g4.z + b4.z;
  o.w = (v.w - mean) * inv * g4.w + b4.w;
  ((float4*)(out + (size_t)row * 512))[t] = o;
}

// ---------------- transposes / LSTM preps --------------------------------
__global__ void transpose_dl(const float* __restrict__ in, float* __restrict__ outp) {
  const int b = blockIdx.x, t = threadIdx.x;
  for (int idx = t; idx < 25 * 512; idx += 256) {
    int l2 = idx / 512, c = idx % 512;
    outp[((size_t)b * 25 + l2) * 512 + c] = in[((size_t)b * 512 + c) * 25 + l2];
  }
}

// X0[b][t=512][32] f16 from x2[b][25][512] (u>=25 pads = 0)
__global__ __launch_bounds__(256)
void prep_x0r(const float* __restrict__ x2, _Float16* __restrict__ X0) {
  __shared__ float tile[25][516];
  const int b = blockIdx.x, t = threadIdx.x;
  for (int idx = t; idx < 25 * 512; idx += 256) {
    int u = idx >> 9, d = idx & 511;
    tile[u][d] = x2[((size_t)b * 25 + u) * 512 + d];
  }
  __syncthreads();
  for (int idx = t; idx < 512 * 32; idx += 256) {
    int d = idx >> 5, u = idx & 31;
    X0[((size_t)b * 512 + d) * 32 + u] = (u < 25) ? (_Float16)tile[u][d] : (_Float16)0.f;
  }
}

// ---------------- pipelined 32-layer LSTM (fdot2, wave-autonomous) -------
// R9 structure: 512 blocks (32 layers x 16 groups of 8 batches), 256 thr,
// wave owns 2 batches -> zero barriers in the step loop. f16 ring
// [l][b][slot64][32] (1 x 16B staging load/thread, 2B f16 producer
// stores at MALL); ax (bias + Wih*x) precomputed densely before the
// serial h-recurrence. R16: gate divisions via v_rcp_f32.
#define NLAY 32
#define NGRP 16
#define BGRP 8
#define CHT  8
#define NCHK 64
#define RSLOTS 64
#define RCHK (RSLOTS / CHT)
#define RLAY ((size_t)128 * RSLOTS * 32)   // halves per layer region

__device__ __forceinline__ int ld_rlx(int* p) {
  return __hip_atomic_load(p, __ATOMIC_RELAXED, __HIP_MEMORY_SCOPE_AGENT);
}
__device__ __forceinline__ void st_rlx(int* p, int v) {
  __hip_atomic_store(p, v, __ATOMIC_RELAXED, __HIP_MEMORY_SCOPE_AGENT);
}
__device__ __forceinline__ unsigned long long ldq_rlx(const unsigned long long* p) {
  return __hip_atomic_load(p, __ATOMIC_RELAXED, __HIP_MEMORY_SCOPE_AGENT);
}
__device__ __forceinline__ void sth_rlx(_Float16* p, _Float16 v) {
  __hip_atomic_store((unsigned short*)p, __builtin_bit_cast(unsigned short, v),
                     __ATOMIC_RELAXED, __HIP_MEMORY_SCOPE_AGENT);
}

__global__ __launch_bounds__(256) __attribute__((amdgpu_waves_per_eu(2, 2)))
void lstm_pipeline(const _Float16* __restrict__ X0, float* __restrict__ yout,
                   _Float16* __restrict__ ring, int* __restrict__ prod,
                   int* __restrict__ cons,
                   const float* __restrict__ Wih, const float* __restrict__ Whh,
                   const float* __restrict__ bih, const float* __restrict__ bhh) {
  const int l = blockIdx.x / NGRP;
  const int g = blockIdx.x % NGRP;
  const int t = threadIdx.x;
  const int u  = t & 31;
  const int bi = t >> 5;
  const bool active = (u < 25);

  __shared__ _Float16 xbuf[CHT][BGRP][32];  // fragment-ready chunk input
  __shared__ _Float16 hbuf[BGRP][32];       // per-batch h (wave-private)

  // ---- weights packed half2: rows {u,25+u,50+u,75+u} (R5-proven) --------
  h2v wih2[4][13], whh2[4][13];
  float bias_r[4];
  float c_reg = 0.f;
  {
    const int uc = active ? u : 24;
#pragma unroll
    for (int j = 0; j < 4; j++) {
      const float* wi = &Wih[((size_t)l * 100 + j * 25 + uc) * 25];
      const float* wh = &Whh[((size_t)l * 100 + j * 25 + uc) * 25];
#pragma unroll
      for (int k = 0; k < 13; k++) {
        float alo = wi[2 * k], ahi = (2 * k + 1 < 25) ? wi[2 * k + 1] : 0.f;
        float blo = wh[2 * k], bhi = (2 * k + 1 < 25) ? wh[2 * k + 1] : 0.f;
        wih2[j][k] = h2v{(_Float16)alo, (_Float16)ahi};
        whh2[j][k] = h2v{(_Float16)blo, (_Float16)bhi};
      }
      bias_r[j] = bih[l * 100 + j * 25 + uc] + bhh[l * 100 + j * 25 + uc];
    }
  }
  for (int idx = t; idx < BGRP * 32; idx += 256) (&hbuf[0][0])[idx] = (_Float16)0.f;
  __syncthreads();

  // producer out pointers (active threads)
  _Float16* ring_out = ring + (size_t)l * RLAY
                       + ((size_t)(g * BGRP + bi) * RSLOTS) * 32 + u;
  float* yout_out = yout + ((size_t)(g * BGRP + bi) * 512) * 25 + u;

  // staging mapping: thread -> (tc, batch, 8-half segment)
  const int s_tc = t >> 5, s_b2 = (t >> 2) & 7, s_seg = t & 3;

  for (int n = 0; n < NCHK; n++) {
    if (t == 0) {
      if (l > 0) {
        int* p = &prod[(l - 1) * NGRP + g];
        while (ld_rlx(p) < n + 1) __builtin_amdgcn_s_sleep(1);
      }
      if (l < NLAY - 1 && n >= RCHK) {
        int* p = &cons[(l + 1) * NGRP + g];
        while (ld_rlx(p) < n - RCHK + 1) __builtin_amdgcn_s_sleep(1);
      }
    }
    __syncthreads();                                   // (A) poll done
    // ---- stage chunk: ONE 16B load per thread ----
    {
      const int tg = n * CHT + s_tc;
      if (l == 0) {
        const uint4* p = (const uint4*)(X0
            + (((size_t)(g * BGRP + s_b2) * 512) + tg) * 32 + s_seg * 8);
        *(uint4*)&xbuf[s_tc][s_b2][s_seg * 8] = *p;
      } else {
        const unsigned long long* p = (const unsigned long long*)(ring
            + (size_t)(l - 1) * RLAY
            + (((size_t)(g * BGRP + s_b2) * RSLOTS) + (tg & (RSLOTS - 1))) * 32
            + s_seg * 8);
        unsigned long long a = ldq_rlx(p);
        unsigned long long b = ldq_rlx(p + 1);
        *(uint4*)&xbuf[s_tc][s_b2][s_seg * 8] =
            make_uint4((unsigned)a, (unsigned)(a >> 32),
                       (unsigned)b, (unsigned)(b >> 32));
      }
    }
    __syncthreads();                                   // (B) staging visible
    if (t == 0 && l > 0) st_rlx(&cons[l * NGRP + g], n + 1);

    // ---- x-part for all 8 steps: dense, latency-free ----
    float ax[CHT][4];
    if (active) {
#pragma unroll
      for (int tc = 0; tc < CHT; tc++) {
        const unsigned int* xr = (const unsigned int*)&xbuf[tc][bi][0];
        uint4 xa = *(const uint4*)(xr);
        uint4 xb = *(const uint4*)(xr + 4);
        uint4 xc = *(const uint4*)(xr + 8);
        unsigned int xd = xr[12];
        h2v xk[13] = {bch2(xa.x), bch2(xa.y), bch2(xa.z), bch2(xa.w),
                      bch2(xb.x), bch2(xb.y), bch2(xb.z), bch2(xb.w),
                      bch2(xc.x), bch2(xc.y), bch2(xc.z), bch2(xc.w),
                      bch2(xd)};
        float a0 = bias_r[0], a1 = bias_r[1], a2 = bias_r[2], a3 = bias_r[3];
#pragma unroll
        for (int k = 0; k < 13; k++) {
          a0 = fdot2(wih2[0][k], xk[k], a0);
          a1 = fdot2(wih2[1][k], xk[k], a1);
          a2 = fdot2(wih2[2][k], xk[k], a2);
          a3 = fdot2(wih2[3][k], xk[k], a3);
        }
        ax[tc][0] = a0; ax[tc][1] = a1; ax[tc][2] = a2; ax[tc][3] = a3;
      }
    }

    // ---- serial h-recurrence: 8 steps, zero barriers ----
#pragma unroll
    for (int tc = 0; tc < CHT; tc++) {
      const int tg = n * CHT + tc;
      if (active) {
        const unsigned int* hr = (const unsigned int*)&hbuf[bi][0];
        uint4 ha = *(const uint4*)(hr);
        uint4 hb = *(const uint4*)(hr + 4);
        uint4 hc = *(const uint4*)(hr + 8);
        unsigned int hd = hr[12];
        h2v hk[13] = {bch2(ha.x), bch2(ha.y), bch2(ha.z), bch2(ha.w),
                      bch2(hb.x), bch2(hb.y), bch2(hb.z), bch2(hb.w),
                      bch2(hc.x), bch2(hc.y), bch2(hc.z), bch2(hc.w),
                      bch2(hd)};
        float a0 = ax[tc][0], a1 = ax[tc][1], a2 = ax[tc][2], a3 = ax[tc][3];
#pragma unroll
        for (int k = 0; k < 13; k++) {
          a0 = fdot2(whh2[0][k], hk[k], a0);
          a1 = fdot2(whh2[1][k], hk[k], a1);
          a2 = fdot2(whh2[2][k], hk[k], a2);
          a3 = fdot2(whh2[3][k], hk[k], a3);
        }
        float si = sigm_fast(a0);
        float sf = sigm_fast(a1);
        float so = sigm_fast(a3);
        c_reg = sf * c_reg + si * tanh_fast(a2);
        float h = so * tanh_fast(c_reg);
        _Float16 h16 = (_Float16)h;
        hbuf[bi][u] = h16;                             // wave-local
        if (l == NLAY - 1)
          yout_out[(size_t)tg * 25] = h;
        else
          sth_rlx(ring_out + (size_t)(tg & (RSLOTS - 1)) * 32, h16);
      }
    }
    asm volatile("s_waitcnt vmcnt(0)" ::: "memory");   // ring stores at MALL
    __syncthreads();                                   // (C) all waves done
    if (t == 0 && l < NLAY - 1) st_rlx(&prod[l * NGRP + g], n + 1);
  }
}

// =====================================================================
extern "C" void kernel_launch(void* const* d_in, const int* in_sizes, int n_in,
                              void* d_out, int out_size, void* d_ws, size_t ws_size,
                              hipStream_t stream) {
  const float* x     = (const float*)d_in[0];
  const float* cross = (const float*)d_in[1];
  const float* Wq_s = (const float*)d_in[2];  const float* bq_s = (const float*)d_in[3];
  const float* Wk_s = (const float*)d_in[4];  const float* bk_s = (const float*)d_in[5];
  const float* Wv_s = (const float*)d_in[6];  const float* bv_s = (const float*)d_in[7];
  const float* Wo_s = (const float*)d_in[8];  const float* bo_s = (const float*)d_in[9];
  const float* Wq_c = (const float*)d_in[10]; const float* bq_c = (const float*)d_in[11];
  const float* Wk_c = (const float*)d_in[12]; const float* bk_c = (const float*)d_in[13];
  const float* Wv_c = (const float*)d_in[14]; const float* bv_c = (const float*)d_in[15];
  const float* Wo_c = (const float*)d_in[16]; const float* bo_c = (const float*)d_in[17];
  const float* g1 = (const float*)d_in[18]; const float* b1 = (const float*)d_in[19];
  const float* g2 = (const float*)d_in[20]; const float* b2 = (const float*)d_in[21];
  const float* g3 = (const float*)d_in[22]; const float* b3 = (const float*)d_in[23];
  const float* Wih = (const float*)d_in[24];
  const float* Whh = (const float*)d_in[25];
  const float* bih = (const float*)d_in[26];
  const float* bhh = (const float*)d_in[27];
  const float* Wc  = (const float*)d_in[28]; const float* bc = (const float*)d_in[29];
  float* out = (float*)d_out;
  float* ws  = (float*)d_ws;

  // ---- workspace (floats); time-multiplexed regions ---------------------
  constexpr size_t A  = 1638400;    // 3200*512
  constexpr size_t C6 = 6291456;    // 12288*512
  float* x1    = ws;
  float* Qc    = ws + A;
  // self phase
  float* Qs    = ws + 2 * A;
  float* Ks    = ws + 3 * A;
  float* Vs    = ws + 4 * A;
  float* attns = ws + 5 * A;
  float* tmp   = ws + 6 * A;
  float* Ps    = ws + 7 * A;
  // cross phase
  float* Kc    = ws + 2 * A;
  float* Vc    = ws + 2 * A + C6;
  float* attnc = ws + 2 * A + 2 * C6;
  float* Pc    = attnc + A;
  float* tmp2  = ws + 6 * A;
  float* x2    = ws + 3 * A;
  // lstm / post
  _Float16* X0b  = (_Float16*)(ws + 4 * A);      // 128*512*32 halves = 1.05M fl
  float*    youtb = ws + 5 * A;                  // [128][512][25] fp32
  _Float16* ringb = (_Float16*)(ws + 6 * A);     // 31*RLAY = 8.13M halves
  float* ytb   = ws + 2 * A;
  float* fy    = ws + 5 * A;                     // after youtb dead
  _Float16* WTall = (_Float16*)(ws + 20000000);
  int* ctr = (int*)(ws + 21179648);

  dim3 blk(256);
  WPtrs wpq;
  wpq.p[0] = Wq_s; wpq.p[1] = Wk_s; wpq.p[2] = Wv_s; wpq.p[3] = Wo_s;
  wpq.p[4] = Wq_c; wpq.p[5] = Wk_c; wpq.p[6] = Wv_c; wpq.p[7] = Wo_c;
  wpq.p[8] = Wc;
  prep_weights<<<dim3(16, 16, 9), blk, 0, stream>>>(wpq, WTall);
  hipMemsetAsync(ctr, 0, 1024 * sizeof(int), stream);
  _Float16* WT[9];
  for (int i = 0; i < 9; i++) WT[i] = WTall + (size_t)i * 262144;

  // ---- self attention ----
  gemm3<<<dim3(24, 50), blk, 0, stream>>>(x, WT[0], WT[1], WT[2],
                                          bq_s, bk_s, bv_s, Qs, Ks, Vs, 3200);
  attn_scores<25><<<dim3(8, 128), blk, 0, stream>>>(Qs, Ks, Ps);
  attn_out<25><<<dim3(8, 128), blk, 0, stream>>>(Ps, Vs, attns);
  gemm3<<<dim3(8, 50), blk, 0, stream>>>(attns, WT[3], WT[3], WT[3],
                                         bo_s, bo_s, bo_s, tmp, tmp, tmp, 3200);
  add_ln<<<3200, 128, 0, stream>>>(x, tmp, g1, b1, x1);
  // ---- cross attention ----
  gemm3<<<dim3(8, 50), blk, 0, stream>>>(x1, WT[4], WT[4], WT[4],
                                         bq_c, bq_c, bq_c, Qc, Qc, Qc, 3200);
  gemm3<<<dim3(16, 192), blk, 0, stream>>>(cross, WT[5], WT[6], WT[6],
                                           bk_c, bv_c, bv_c, Kc, Vc, Vc, 12288);
  attn_scores<96><<<dim3(8, 128), blk, 0, stream>>>(Qc, Kc, Pc);
  attn_out<96><<<dim3(8, 128), blk, 0, stream>>>(Pc, Vc, attnc);
  gemm3<<<dim3(8, 50), blk, 0, stream>>>(attnc, WT[7], WT[7], WT[7],
                                         bo_c, bo_c, bo_c, tmp2, tmp2, tmp2, 3200);
  add_ln<<<3200, 128, 0, stream>>>(x1, tmp2, g2, b2, x2);
  // ---- LSTM over feature axis ----
  prep_x0r<<<128, 256, 0, stream>>>(x2, X0b);
  lstm_pipeline<<<NLAY * NGRP, 256, 0, stream>>>(X0b, youtb, ringb, ctr, ctr + 512,
                                                 Wih, Whh, bih, bhh);
  // ---- pointwise conv over channels + final LN ----
  transpose_dl<<<128, 256, 0, stream>>>(youtb, ytb);
  gemm3<<<dim3(8, 50), blk, 0, stream>>>(ytb, WT[8], WT[8], WT[8],
                                         bc, bc, bc, fy, fy, fy, 3200);
  add_ln<<<3200, 128, 0, stream>>>(x2, fy, g3, b3, out);
}

// Round 8
// 912.252 us; speedup vs baseline: 3.7114x; 1.0222x over previous
//
#include <hip/hip_runtime.h>

// =====================================================================
// DecoderLayer: selfMHA -> LN -> crossMHA -> LN -> 32xLSTM(pipelined)
//               -> pointwise conv -> LN
// Round 17: wave-autonomous LSTM pipelines. R16 (932us total, lstm 613)
//   proved chain-shortening multiplies by the 95 periods; the remaining
//   handoff is 3 __syncthreads + t0-poll-wake per chunk, which yokes 4
//   independent batch-pair pipelines into block lockstep. Data flow is
//   already wave-local (disjoint xbuf/hbuf rows, ring regions, outputs)
//   -> per-(layer,pipe) counters (32x64), all-lane wave polling (R12-
//   proven), wave stages its OWN 2 batches, lgkmcnt(0) replaces barrier
//   B, vmcnt(0)+lane0 signal replaces barrier C. ZERO __syncthreads.
//   R9 lag-1 protocol per pipe; arithmetic identical to R16 (rcp_fast).
// =====================================================================

#define EPS_LN 1e-5f

typedef _Float16 h2v __attribute__((ext_vector_type(2)));
typedef _Float16 h8v __attribute__((ext_vector_type(8)));
typedef float    f4v __attribute__((ext_vector_type(4)));

#if defined(__has_builtin)
#if __has_builtin(__builtin_amdgcn_fdot2)
#define HAVE_FDOT2 1
#endif
#if __has_builtin(__builtin_amdgcn_rcpf)
#define HAVE_RCPF 1
#endif
#endif

__device__ __forceinline__ float fdot2(h2v a, h2v b, float c) {
#ifdef HAVE_FDOT2
  return __builtin_amdgcn_fdot2(a, b, c, false);
#else
  return c + (float)a.x * (float)b.x + (float)a.y * (float)b.y;
#endif
}
__device__ __forceinline__ h2v bch2(unsigned int u) {
  return __builtin_bit_cast(h2v, u);
}
__device__ __forceinline__ float rcp_fast(float x) {
#ifdef HAVE_RCPF
  return __builtin_amdgcn_rcpf(x);
#else
  return 1.f / x;
#endif
}
__device__ __forceinline__ float sigm_fast(float x) {
  return rcp_fast(1.f + __expf(-x));
}
__device__ __forceinline__ float tanh_fast(float x) {
  return 1.f - 2.f * rcp_fast(1.f + __expf(2.f * x));
}

// ---------------- fused weight prep: 8 transposes + 1 straight cvt -------
struct WPtrs { const float* p[9]; };

__global__ __launch_bounds__(256)
void prep_weights(WPtrs w, _Float16* __restrict__ dst) {
  __shared__ float tile[32][33];
  const int z = blockIdx.z;
  const int tx = threadIdx.x & 31, ty = threadIdx.x >> 5;
  const int bx = blockIdx.x, by = blockIdx.y;
  const float* in = w.p[z];
  _Float16* outp = dst + (size_t)z * 262144;
  if (z < 8) {
#pragma unroll
    for (int i = 0; i < 4; i++)
      tile[ty + i * 8][tx] = in[(size_t)(by * 32 + ty + i * 8) * 512 + bx * 32 + tx];
    __syncthreads();
#pragma unroll
    for (int i = 0; i < 4; i++)
      outp[(size_t)(bx * 32 + ty + i * 8) * 512 + by * 32 + tx] = (_Float16)tile[tx][ty + i * 8];
  } else {
#pragma unroll
    for (int i = 0; i < 4; i++) {
      size_t off = (size_t)(by * 32 + ty + i * 8) * 512 + bx * 32 + tx;
      outp[off] = (_Float16)in[off];
    }
  }
}

// ---------------- f16 MFMA GEMM, fp32 A staged+converted in LDS ----------
__global__ __launch_bounds__(256)
void gemm3(const float* __restrict__ A,
           const _Float16* __restrict__ BT0, const _Float16* __restrict__ BT1,
           const _Float16* __restrict__ BT2,
           const float* __restrict__ bias0, const float* __restrict__ bias1,
           const float* __restrict__ bias2,
           float* __restrict__ C0, float* __restrict__ C1, float* __restrict__ C2,
           int M) {
  __shared__ _Float16 Asld[64 * 40];
  __shared__ _Float16 Bsld[64 * 40];
  const int t = threadIdx.x;
  const int which = blockIdx.x >> 3;
  const int n0 = (blockIdx.x & 7) * 64;
  const int m0 = blockIdx.y * 64;
  const _Float16* BT = (which == 0) ? BT0 : (which == 1) ? BT1 : BT2;
  const float* bias  = (which == 0) ? bias0 : (which == 1) ? bias1 : bias2;
  float* C           = (which == 0) ? C0 : (which == 1) ? C1 : C2;

  const int r = t >> 2, q = t & 3;
  const int w = t >> 6;
  const int lane = t & 63;
  const int lm = lane & 15, q8 = lane >> 4;

  f4v acc[4] = {};
  for (int k0 = 0; k0 < 512; k0 += 32) {
    __syncthreads();
    float4 f0 = *(const float4*)&A[(size_t)(m0 + r) * 512 + k0 + q * 8];
    float4 f1 = *(const float4*)&A[(size_t)(m0 + r) * 512 + k0 + q * 8 + 4];
    h8v hvv = {(_Float16)f0.x, (_Float16)f0.y, (_Float16)f0.z, (_Float16)f0.w,
               (_Float16)f1.x, (_Float16)f1.y, (_Float16)f1.z, (_Float16)f1.w};
    *(h8v*)&Asld[r * 40 + q * 8] = hvv;
    *(uint4*)&Bsld[r * 40 + q * 8] = *(const uint4*)&BT[(size_t)(n0 + r) * 512 + k0 + q * 8];
    __syncthreads();
    h8v a = *(const h8v*)&Asld[(w * 16 + lm) * 40 + q8 * 8];
#pragma unroll
    for (int nt = 0; nt < 4; nt++) {
      h8v b = *(const h8v*)&Bsld[(nt * 16 + lm) * 40 + q8 * 8];
      acc[nt] = __builtin_amdgcn_mfma_f32_16x16x32_f16(a, b, acc[nt], 0, 0, 0);
    }
  }
#pragma unroll
  for (int nt = 0; nt < 4; nt++) {
    int gn = n0 + nt * 16 + lm;
    float bv = bias[gn];
#pragma unroll
    for (int rg = 0; rg < 4; rg++) {
      int gm = m0 + w * 16 + q8 * 4 + rg;
      C[(size_t)gm * 512 + gn] = acc[nt][rg] + bv;
    }
  }
}

// ---------------- attention: scores then softmax+PV, per (b,h) -----------
template <int S>
__global__ __launch_bounds__(256)
void attn_scores(const float* __restrict__ Q, const float* __restrict__ K,
                 float* __restrict__ P) {
  __shared__ float Qs[25][64];
  __shared__ float Ks[S][65];
  const int h = blockIdx.x, b = blockIdx.y, t = threadIdx.x;
  for (int idx = t; idx < 25 * 64; idx += 256) {
    int l = idx >> 6, e = idx & 63;
    Qs[l][e] = Q[(b * 25 + l) * 512 + h * 64 + e];
  }
  for (int idx = t; idx < S * 64; idx += 256) {
    int s = idx >> 6, e = idx & 63;
    Ks[s][e] = K[(b * S + s) * 512 + h * 64 + e];
  }
  __syncthreads();
  float* Pb = P + (size_t)(b * 8 + h) * 25 * S;
  for (int idx = t; idx < 25 * S; idx += 256) {
    int l = idx / S, s = idx % S;
    float acc = 0.f;
#pragma unroll
    for (int e = 0; e < 64; e++) acc += Qs[l][e] * Ks[s][e];
    Pb[idx] = acc * 0.125f;
  }
}

template <int S>
__global__ __launch_bounds__(256)
void attn_out(const float* __restrict__ P, const float* __restrict__ V,
              float* __restrict__ O) {
  __shared__ float Ps[25][S];
  __shared__ float Vs[S][64];
  const int h = blockIdx.x, b = blockIdx.y, t = threadIdx.x;
  const float* Pb = P + (size_t)(b * 8 + h) * 25 * S;
  for (int idx = t; idx < 25 * S; idx += 256) Ps[idx / S][idx % S] = Pb[idx];
  for (int idx = t; idx < S * 64; idx += 256) {
    int s = idx >> 6, e = idx & 63;
    Vs[s][e] = V[(b * S + s) * 512 + h * 64 + e];
  }
  __syncthreads();
  if (t < 25) {
    float mx = -1e30f;
    for (int s = 0; s < S; s++) mx = fmaxf(mx, Ps[t][s]);
    float sum = 0.f;
    for (int s = 0; s < S; s++) { float p = __expf(Ps[t][s] - mx); Ps[t][s] = p; sum += p; }
    float r = 1.f / sum;
    for (int s = 0; s < S; s++) Ps[t][s] *= r;
  }
  __syncthreads();
  for (int idx = t; idx < 25 * 64; idx += 256) {
    int l = idx >> 6, e = idx & 63;
    float acc = 0.f;
    for (int s = 0; s < S; s++) acc += Ps[l][s] * Vs[s][e];
    O[(b * 25 + l) * 512 + h * 64 + e] = acc;
  }
}

// ---------------- fused residual-add + LayerNorm (rows of 512) -----------
__global__ __launch_bounds__(128)
void add_ln(const float* __restrict__ a, const float* __restrict__ b,
            const float* __restrict__ gw, const float* __restrict__ bw,
            float* __restrict__ out) {
  const int row = blockIdx.x, t = threadIdx.x;
  float4 va = ((const float4*)(a + (size_t)row * 512))[t];
  float4 vb = ((const float4*)(b + (size_t)row * 512))[t];
  float4 v = make_float4(va.x + vb.x, va.y + vb.y, va.z + vb.z, va.w + vb.w);
  float s = v.x + v.y + v.z + v.w;
  float q = v.x * v.x + v.y * v.y + v.z * v.z + v.w * v.w;
#pragma unroll
  for (int off = 32; off > 0; off >>= 1) {
    s += __shfl_down(s, off);
    q += __shfl_down(q, off);
  }
  __shared__ float red[4];
  if ((t & 63) == 0) { red[(t >> 6) * 2] = s; red[(t >> 6) * 2 + 1] = q; }
  __syncthreads();
  float S_ = red[0] + red[2], Q_ = red[1] + red[3];
  float mean = S_ * (1.f / 512.f);
  float var  = Q_ * (1.f / 512.f) - mean * mean;
  float inv  = rsqrtf(var + EPS_LN);
  float4 g4 = ((const float4*)gw)[t];
  float4 b4 = ((const float4*)bw)[t];
  float4 o;
  o.x = (v.x - mean) * inv * g4.x + b4.x;
  o.y = (v.y - mean) * inv * g4.y + b4.y;
  o.z = (v.z - mean) * inv * g4.z + b4.z;
  o.w = (v.w - mean) * inv * g4.w + b4.w;
  ((float4*)(out + (size_t)row * 512))[t] = o;
}

// ---------------- transposes / LSTM preps --------------------------------
__global__ void transpose_dl(const float* __restrict__ in, float* __restrict__ outp) {
  const int b = blockIdx.x, t = threadIdx.x;
  for (int idx = t; idx < 25 * 512; idx += 256) {
    int l2 = idx / 512, c = idx % 512;
    outp[((size_t)b * 25 + l2) * 512 + c] = in[((size_t)b * 512 + c) * 25 + l2];
  }
}

// X0[b][t=512][32] f16 from x2[b][25][512] (u>=25 pads = 0)
__global__ __launch_bounds__(256)
void prep_x0r(const float* __restrict__ x2, _Float16* __restrict__ X0) {
  __shared__ float tile[25][516];
  const int b = blockIdx.x, t = threadIdx.x;
  for (int idx = t; idx < 25 * 512; idx += 256) {
    int u = idx >> 9, d = idx & 511;
    tile[u][d] = x2[((size_t)b * 25 + u) * 512 + d];
  }
  __syncthreads();
  for (int idx = t; idx < 512 * 32; idx += 256) {
    int d = idx >> 5, u = idx & 31;
    X0[((size_t)b * 512 + d) * 32 + u] = (u < 25) ? (_Float16)tile[u][d] : (_Float16)0.f;
  }
}

// ---------------- pipelined 32-layer LSTM (fdot2, wave-autonomous) -------
// R17: 512 blocks x 4 waves = 2048 waves = 32 layers x 64 independent
// batch-pair pipelines. Each wave: polls its own per-pipe counters
// (all-lane uniform spin), stages its OWN 2 batches (1 uint4/lane),
// lgkmcnt(0) instead of barrier B, vmcnt(0)+lane0 signal instead of
// barrier C. No __syncthreads anywhere. Consumption code = R16.
#define NLAY 32
#define NGRP 16
#define BGRP 8
#define NPIPE 64
#define CHT  8
#define NCHK 64
#define RSLOTS 64
#define RCHK (RSLOTS / CHT)
#define RLAY ((size_t)128 * RSLOTS * 32)   // halves per layer region

__device__ __forceinline__ int ld_rlx(int* p) {
  return __hip_atomic_load(p, __ATOMIC_RELAXED, __HIP_MEMORY_SCOPE_AGENT);
}
__device__ __forceinline__ void st_rlx(int* p, int v) {
  __hip_atomic_store(p, v, __ATOMIC_RELAXED, __HIP_MEMORY_SCOPE_AGENT);
}
__device__ __forceinline__ unsigned long long ldq_rlx(const unsigned long long* p) {
  return __hip_atomic_load(p, __ATOMIC_RELAXED, __HIP_MEMORY_SCOPE_AGENT);
}
__device__ __forceinline__ void sth_rlx(_Float16* p, _Float16 v) {
  __hip_atomic_store((unsigned short*)p, __builtin_bit_cast(unsigned short, v),
                     __ATOMIC_RELAXED, __HIP_MEMORY_SCOPE_AGENT);
}

__global__ __launch_bounds__(256) __attribute__((amdgpu_waves_per_eu(2, 2)))
void lstm_pipeline(const _Float16* __restrict__ X0, float* __restrict__ yout,
                   _Float16* __restrict__ ring, int* __restrict__ prod,
                   int* __restrict__ cons,
                   const float* __restrict__ Wih, const float* __restrict__ Whh,
                   const float* __restrict__ bih, const float* __restrict__ bhh) {
  const int l = blockIdx.x / NGRP;
  const int g = blockIdx.x % NGRP;
  const int t = threadIdx.x;
  const int lane = t & 63;
  const int wv = t >> 6;                 // wave 0..3
  const int u  = t & 31;
  const int bi = t >> 5;                 // local batch slot 0..7 (= 2wv + half)
  const int p  = g * 4 + wv;             // pipe 0..63 (batch pair)
  const bool active = (u < 25);

  __shared__ _Float16 xbuf[CHT][BGRP][32];  // per-wave rows disjoint
  __shared__ _Float16 hbuf[BGRP][32];       // per-wave rows disjoint

  // ---- weights packed half2: rows {u,25+u,50+u,75+u} (R5-proven) --------
  h2v wih2[4][13], whh2[4][13];
  float bias_r[4];
  float c_reg = 0.f;
  {
    const int uc = active ? u : 24;
#pragma unroll
    for (int j = 0; j < 4; j++) {
      const float* wi = &Wih[((size_t)l * 100 + j * 25 + uc) * 25];
      const float* wh = &Whh[((size_t)l * 100 + j * 25 + uc) * 25];
#pragma unroll
      for (int k = 0; k < 13; k++) {
        float alo = wi[2 * k], ahi = (2 * k + 1 < 25) ? wi[2 * k + 1] : 0.f;
        float blo = wh[2 * k], bhi = (2 * k + 1 < 25) ? wh[2 * k + 1] : 0.f;
        wih2[j][k] = h2v{(_Float16)alo, (_Float16)ahi};
        whh2[j][k] = h2v{(_Float16)blo, (_Float16)bhi};
      }
      bias_r[j] = bih[l * 100 + j * 25 + uc] + bhh[l * 100 + j * 25 + uc];
    }
  }
  // wave-local hbuf init: lane 0..63 covers this wave's 2 batch rows
  hbuf[2 * wv + (lane >> 5)][lane & 31] = (_Float16)0.f;

  // producer out pointers (active threads)
  _Float16* ring_out = ring + (size_t)l * RLAY
                       + ((size_t)(g * BGRP + bi) * RSLOTS) * 32 + u;
  float* yout_out = yout + ((size_t)(g * BGRP + bi) * 512) * 25 + u;

  // wave-local staging map: lane -> (tc, own half, 8-half segment)
  const int s_tc = lane >> 3;                 // 0..7
  const int s_b2 = 2 * wv + ((lane >> 2) & 1);
  const int s_seg = lane & 3;

  int* prod_in   = prod + (l - 1) * NPIPE + p;   // valid only when l > 0
  int* prod_out  = prod + l * NPIPE + p;         // valid only when l < NLAY-1
  int* cons_self = cons + l * NPIPE + p;         // valid only when l > 0
  int* cons_up   = cons + (l + 1) * NPIPE + p;   // valid only when l < NLAY-1

  for (int n = 0; n < NCHK; n++) {
    // ---- wave-uniform polls (all lanes, one transaction) ----
    if (l > 0) {
      while (ld_rlx(prod_in) < n + 1) __builtin_amdgcn_s_sleep(1);
    }
    if (l < NLAY - 1 && n >= RCHK) {
      while (ld_rlx(cons_up) < n - RCHK + 1) __builtin_amdgcn_s_sleep(1);
    }
    asm volatile("" ::: "memory");   // no hoisting of data loads above poll

    // ---- stage own 2 batches: ONE 16B load per lane ----
    {
      const int tg = n * CHT + s_tc;
      if (l == 0) {
        const uint4* p4 = (const uint4*)(X0
            + (((size_t)(g * BGRP + s_b2) * 512) + tg) * 32 + s_seg * 8);
        *(uint4*)&xbuf[s_tc][s_b2][s_seg * 8] = *p4;
      } else {
        const unsigned long long* p8 = (const unsigned long long*)(ring
            + (size_t)(l - 1) * RLAY
            + (((size_t)(g * BGRP + s_b2) * RSLOTS) + (tg & (RSLOTS - 1))) * 32
            + s_seg * 8);
        unsigned long long a = ldq_rlx(p8);
        unsigned long long b = ldq_rlx(p8 + 1);
        *(uint4*)&xbuf[s_tc][s_b2][s_seg * 8] =
            make_uint4((unsigned)a, (unsigned)(a >> 32),
                       (unsigned)b, (unsigned)(b >> 32));
      }
    }
    asm volatile("s_waitcnt lgkmcnt(0)" ::: "memory");  // staging visible (wave-local)
    if (lane == 0 && l > 0) st_rlx(cons_self, n + 1);

    // ---- x-part for all 8 steps: dense, latency-free ----
    float ax[CHT][4];
    if (active) {
#pragma unroll
      for (int tc = 0; tc < CHT; tc++) {
        const unsigned int* xr = (const unsigned int*)&xbuf[tc][bi][0];
        uint4 xa = *(const uint4*)(xr);
        uint4 xb = *(const uint4*)(xr + 4);
        uint4 xc = *(const uint4*)(xr + 8);
        unsigned int xd = xr[12];
        h2v xk[13] = {bch2(xa.x), bch2(xa.y), bch2(xa.z), bch2(xa.w),
                      bch2(xb.x), bch2(xb.y), bch2(xb.z), bch2(xb.w),
                      bch2(xc.x), bch2(xc.y), bch2(xc.z), bch2(xc.w),
                      bch2(xd)};
        float a0 = bias_r[0], a1 = bias_r[1], a2 = bias_r[2], a3 = bias_r[3];
#pragma unroll
        for (int k = 0; k < 13; k++) {
          a0 = fdot2(wih2[0][k], xk[k], a0);
          a1 = fdot2(wih2[1][k], xk[k], a1);
          a2 = fdot2(wih2[2][k], xk[k], a2);
          a3 = fdot2(wih2[3][k], xk[k], a3);
        }
        ax[tc][0] = a0; ax[tc][1] = a1; ax[tc][2] = a2; ax[tc][3] = a3;
      }
    }

    // ---- serial h-recurrence: 8 steps, wave-local ----
#pragma unroll
    for (int tc = 0; tc < CHT; tc++) {
      const int tg = n * CHT + tc;
      if (active) {
        const unsigned int* hr = (const unsigned int*)&hbuf[bi][0];
        uint4 ha = *(const uint4*)(hr);
        uint4 hb = *(const uint4*)(hr + 4);
        uint4 hc = *(const uint4*)(hr + 8);
        unsigned int hd = hr[12];
        h2v hk[13] = {bch2(ha.x), bch2(ha.y), bch2(ha.z), bch2(ha.w),
                      bch2(hb.x), bch2(hb.y), bch2(hb.z), bch2(hb.w),
                      bch2(hc.x), bch2(hc.y), bch2(hc.z), bch2(hc.w),
                      bch2(hd)};
        float a0 = ax[tc][0], a1 = ax[tc][1], a2 = ax[tc][2], a3 = ax[tc][3];
#pragma unroll
        for (int k = 0; k < 13; k++) {
          a0 = fdot2(whh2[0][k], hk[k], a0);
          a1 = fdot2(whh2[1][k], hk[k], a1);
          a2 = fdot2(whh2[2][k], hk[k], a2);
          a3 = fdot2(whh2[3][k], hk[k], a3);
        }
        float si = sigm_fast(a0);
        float sf = sigm_fast(a1);
        float so = sigm_fast(a3);
        c_reg = sf * c_reg + si * tanh_fast(a2);
        float h = so * tanh_fast(c_reg);
        _Float16 h16 = (_Float16)h;
        hbuf[bi][u] = h16;                             // wave-local
        if (l == NLAY - 1)
          yout_out[(size_t)tg * 25] = h;
        else
          sth_rlx(ring_out + (size_t)(tg & (RSLOTS - 1)) * 32, h16);
      }
    }
    asm volatile("s_waitcnt vmcnt(0)" ::: "memory");   // ring stores at MALL
    if (lane == 0 && l < NLAY - 1) st_rlx(prod_out, n + 1);
  }
}

// =====================================================================
extern "C" void kernel_launch(void* const* d_in, const int* in_sizes, int n_in,
                              void* d_out, int out_size, void* d_ws, size_t ws_size,
                              hipStream_t stream) {
  const float* x     = (const float*)d_in[0];
  const float* cross = (const float*)d_in[1];
  const float* Wq_s = (const float*)d_in[2];  const float* bq_s = (const float*)d_in[3];
  const float* Wk_s = (const float*)d_in[4];  const float* bk_s = (const float*)d_in[5];
  const float* Wv_s = (const float*)d_in[6];  const float* bv_s = (const float*)d_in[7];
  const float* Wo_s = (const float*)d_in[8];  const float* bo_s = (const float*)d_in[9];
  const float* Wq_c = (const float*)d_in[10]; const float* bq_c = (const float*)d_in[11];
  const float* Wk_c = (const float*)d_in[12]; const float* bk_c = (const float*)d_in[13];
  const float* Wv_c = (const float*)d_in[14]; const float* bv_c = (const float*)d_in[15];
  const float* Wo_c = (const float*)d_in[16]; const float* bo_c = (const float*)d_in[17];
  const float* g1 = (const float*)d_in[18]; const float* b1 = (const float*)d_in[19];
  const float* g2 = (const float*)d_in[20]; const float* b2 = (const float*)d_in[21];
  const float* g3 = (const float*)d_in[22]; const float* b3 = (const float*)d_in[23];
  const float* Wih = (const float*)d_in[24];
  const float* Whh = (const float*)d_in[25];
  const float* bih = (const float*)d_in[26];
  const float* bhh = (const float*)d_in[27];
  const float* Wc  = (const float*)d_in[28]; const float* bc = (const float*)d_in[29];
  float* out = (float*)d_out;
  float* ws  = (float*)d_ws;

  // ---- workspace (floats); time-multiplexed regions ---------------------
  constexpr size_t A  = 1638400;    // 3200*512
  constexpr size_t C6 = 6291456;    // 12288*512
  float* x1    = ws;
  float* Qc    = ws + A;
  // self phase
  float* Qs    = ws + 2 * A;
  float* Ks    = ws + 3 * A;
  float* Vs    = ws + 4 * A;
  float* attns = ws + 5 * A;
  float* tmp   = ws + 6 * A;
  float* Ps    = ws + 7 * A;
  // cross phase
  float* Kc    = ws + 2 * A;
  float* Vc    = ws + 2 * A + C6;
  float* attnc = ws + 2 * A + 2 * C6;
  float* Pc    = attnc + A;
  float* tmp2  = ws + 6 * A;
  float* x2    = ws + 3 * A;
  // lstm / post
  _Float16* X0b  = (_Float16*)(ws + 4 * A);      // 128*512*32 halves = 1.05M fl
  float*    youtb = ws + 5 * A;                  // [128][512][25] fp32
  _Float16* ringb = (_Float16*)(ws + 6 * A);     // 31*RLAY = 8.13M halves
  float* ytb   = ws + 2 * A;
  float* fy    = ws + 5 * A;                     // after youtb dead
  _Float16* WTall = (_Float16*)(ws + 20000000);
  int* ctr = (int*)(ws + 21179648);

  dim3 blk(256);
  WPtrs wpq;
  wpq.p[0] = Wq_s; wpq.p[1] = Wk_s; wpq.p[2] = Wv_s; wpq.p[3] = Wo_s;
  wpq.p[4] = Wq_c; wpq.p[5] = Wk_c; wpq.p[6] = Wv_c; wpq.p[7] = Wo_c;
  wpq.p[8] = Wc;
  prep_weights<<<dim3(16, 16, 9), blk, 0, stream>>>(wpq, WTall);
  hipMemsetAsync(ctr, 0, 4096 * sizeof(int), stream);
  _Float16* WT[9];
  for (int i = 0; i < 9; i++) WT[i] = WTall + (size_t)i * 262144;

  // ---- self attention ----
  gemm3<<<dim3(24, 50), blk, 0, stream>>>(x, WT[0], WT[1], WT[2],
                                          bq_s, bk_s, bv_s, Qs, Ks, Vs, 3200);
  attn_scores<25><<<dim3(8, 128), blk, 0, stream>>>(Qs, Ks, Ps);
  attn_out<25><<<dim3(8, 128), blk, 0, stream>>>(Ps, Vs, attns);
  gemm3<<<dim3(8, 50), blk, 0, stream>>>(attns, WT[3], WT[3], WT[3],
                                         bo_s, bo_s, bo_s, tmp, tmp, tmp, 3200);
  add_ln<<<3200, 128, 0, stream>>>(x, tmp, g1, b1, x1);
  // ---- cross attention ----
  gemm3<<<dim3(8, 50), blk, 0, stream>>>(x1, WT[4], WT[4], WT[4],
                                         bq_c, bq_c, bq_c, Qc, Qc, Qc, 3200);
  gemm3<<<dim3(16, 192), blk, 0, stream>>>(cross, WT[5], WT[6], WT[6],
                                           bk_c, bv_c, bv_c, Kc, Vc, Vc, 12288);
  attn_scores<96><<<dim3(8, 128), blk, 0, stream>>>(Qc, Kc, Pc);
  attn_out<96><<<dim3(8, 128), blk, 0, stream>>>(Pc, Vc, attnc);
  gemm3<<<dim3(8, 50), blk, 0, stream>>>(attnc, WT[7], WT[7], WT[7],
                                         bo_c, bo_c, bo_c, tmp2, tmp2, tmp2, 3200);
  add_ln<<<3200, 128, 0, stream>>>(x1, tmp2, g2, b2, x2);
  // ---- LSTM over feature axis ----
  prep_x0r<<<128, 256, 0, stream>>>(x2, X0b);
  lstm_pipeline<<<NLAY * NGRP, 256, 0, stream>>>(X0b, youtb, ringb, ctr, ctr + 2048,
                                                 Wih, Whh, bih, bhh);
  // ---- pointwise conv over channels + final LN ----
  transpose_dl<<<128, 256, 0, stream>>>(youtb, ytb);
  gemm3<<<dim3(8, 50), blk, 0, stream>>>(ytb, WT[8], WT[8], WT[8],
                                         bc, bc, bc, fy, fy, fy, 3200);
  add_ln<<<3200, 128, 0, stream>>>(x2, fy, g3, b3, out);
}

// Round 10
// 841.825 us; speedup vs baseline: 4.0219x; 1.0837x over previous
//
#include <hip/hip_runtime.h>

// =====================================================================
// DecoderLayer: selfMHA -> LN -> crossMHA -> LN -> 32xLSTM(pipelined)
//               -> pointwise conv -> LN
// Round 19: R18 retry (container failed with no counters; protocol
//   re-audit found no deadlock — suspect infra). Single hardening
//   delta vs R18: explicit s_waitcnt lgkmcnt(0) before the upstream
//   LDS-slot-free signal (was relying on DS in-order retire).
//   Structure: block = 4 consecutive layers (one per wave) x 1
//   batch-pair pipe; 24/31 hops via LDS SPSC rings (4 slots), only
//   wv3->wv0 hops via the proven global ring protocol. Arithmetic
//   identical to R16/R17.
// =====================================================================

#define EPS_LN 1e-5f

typedef _Float16 h2v __attribute__((ext_vector_type(2)));
typedef _Float16 h8v __attribute__((ext_vector_type(8)));
typedef float    f4v __attribute__((ext_vector_type(4)));

#if defined(__has_builtin)
#if __has_builtin(__builtin_amdgcn_fdot2)
#define HAVE_FDOT2 1
#endif
#if __has_builtin(__builtin_amdgcn_rcpf)
#define HAVE_RCPF 1
#endif
#endif

__device__ __forceinline__ float fdot2(h2v a, h2v b, float c) {
#ifdef HAVE_FDOT2
  return __builtin_amdgcn_fdot2(a, b, c, false);
#else
  return c + (float)a.x * (float)b.x + (float)a.y * (float)b.y;
#endif
}
__device__ __forceinline__ h2v bch2(unsigned int u) {
  return __builtin_bit_cast(h2v, u);
}
__device__ __forceinline__ float rcp_fast(float x) {
#ifdef HAVE_RCPF
  return __builtin_amdgcn_rcpf(x);
#else
  return 1.f / x;
#endif
}
__device__ __forceinline__ float sigm_fast(float x) {
  return rcp_fast(1.f + __expf(-x));
}
__device__ __forceinline__ float tanh_fast(float x) {
  return 1.f - 2.f * rcp_fast(1.f + __expf(2.f * x));
}

// ---------------- fused weight prep: 8 transposes + 1 straight cvt -------
struct WPtrs { const float* p[9]; };

__global__ __launch_bounds__(256)
void prep_weights(WPtrs w, _Float16* __restrict__ dst) {
  __shared__ float tile[32][33];
  const int z = blockIdx.z;
  const int tx = threadIdx.x & 31, ty = threadIdx.x >> 5;
  const int bx = blockIdx.x, by = blockIdx.y;
  const float* in = w.p[z];
  _Float16* outp = dst + (size_t)z * 262144;
  if (z < 8) {
#pragma unroll
    for (int i = 0; i < 4; i++)
      tile[ty + i * 8][tx] = in[(size_t)(by * 32 + ty + i * 8) * 512 + bx * 32 + tx];
    __syncthreads();
#pragma unroll
    for (int i = 0; i < 4; i++)
      outp[(size_t)(bx * 32 + ty + i * 8) * 512 + by * 32 + tx] = (_Float16)tile[tx][ty + i * 8];
  } else {
#pragma unroll
    for (int i = 0; i < 4; i++) {
      size_t off = (size_t)(by * 32 + ty + i * 8) * 512 + bx * 32 + tx;
      outp[off] = (_Float16)in[off];
    }
  }
}

// ---------------- f16 MFMA GEMM, fp32 A staged+converted in LDS ----------
__global__ __launch_bounds__(256)
void gemm3(const float* __restrict__ A,
           const _Float16* __restrict__ BT0, const _Float16* __restrict__ BT1,
           const _Float16* __restrict__ BT2,
           const float* __restrict__ bias0, const float* __restrict__ bias1,
           const float* __restrict__ bias2,
           float* __restrict__ C0, float* __restrict__ C1, float* __restrict__ C2,
           int M) {
  __shared__ _Float16 Asld[64 * 40];
  __shared__ _Float16 Bsld[64 * 40];
  const int t = threadIdx.x;
  const int which = blockIdx.x >> 3;
  const int n0 = (blockIdx.x & 7) * 64;
  const int m0 = blockIdx.y * 64;
  const _Float16* BT = (which == 0) ? BT0 : (which == 1) ? BT1 : BT2;
  const float* bias  = (which == 0) ? bias0 : (which == 1) ? bias1 : bias2;
  float* C           = (which == 0) ? C0 : (which == 1) ? C1 : C2;

  const int r = t >> 2, q = t & 3;
  const int w = t >> 6;
  const int lane = t & 63;
  const int lm = lane & 15, q8 = lane >> 4;

  f4v acc[4] = {};
  for (int k0 = 0; k0 < 512; k0 += 32) {
    __syncthreads();
    float4 f0 = *(const float4*)&A[(size_t)(m0 + r) * 512 + k0 + q * 8];
    float4 f1 = *(const float4*)&A[(size_t)(m0 + r) * 512 + k0 + q * 8 + 4];
    h8v hvv = {(_Float16)f0.x, (_Float16)f0.y, (_Float16)f0.z, (_Float16)f0.w,
               (_Float16)f1.x, (_Float16)f1.y, (_Float16)f1.z, (_Float16)f1.w};
    *(h8v*)&Asld[r * 40 + q * 8] = hvv;
    *(uint4*)&Bsld[r * 40 + q * 8] = *(const uint4*)&BT[(size_t)(n0 + r) * 512 + k0 + q * 8];
    __syncthreads();
    h8v a = *(const h8v*)&Asld[(w * 16 + lm) * 40 + q8 * 8];
#pragma unroll
    for (int nt = 0; nt < 4; nt++) {
      h8v b = *(const h8v*)&Bsld[(nt * 16 + lm) * 40 + q8 * 8];
      acc[nt] = __builtin_amdgcn_mfma_f32_16x16x32_f16(a, b, acc[nt], 0, 0, 0);
    }
  }
#pragma unroll
  for (int nt = 0; nt < 4; nt++) {
    int gn = n0 + nt * 16 + lm;
    float bv = bias[gn];
#pragma unroll
    for (int rg = 0; rg < 4; rg++) {
      int gm = m0 + w * 16 + q8 * 4 + rg;
      C[(size_t)gm * 512 + gn] = acc[nt][rg] + bv;
    }
  }
}

// ---------------- attention: scores then softmax+PV, per (b,h) -----------
template <int S>
__global__ __launch_bounds__(256)
void attn_scores(const float* __restrict__ Q, const float* __restrict__ K,
                 float* __restrict__ P) {
  __shared__ float Qs[25][64];
  __shared__ float Ks[S][65];
  const int h = blockIdx.x, b = blockIdx.y, t = threadIdx.x;
  for (int idx = t; idx < 25 * 64; idx += 256) {
    int l = idx >> 6, e = idx & 63;
    Qs[l][e] = Q[(b * 25 + l) * 512 + h * 64 + e];
  }
  for (int idx = t; idx < S * 64; idx += 256) {
    int s = idx >> 6, e = idx & 63;
    Ks[s][e] = K[(b * S + s) * 512 + h * 64 + e];
  }
  __syncthreads();
  float* Pb = P + (size_t)(b * 8 + h) * 25 * S;
  for (int idx = t; idx < 25 * S; idx += 256) {
    int l = idx / S, s = idx % S;
    float acc = 0.f;
#pragma unroll
    for (int e = 0; e < 64; e++) acc += Qs[l][e] * Ks[s][e];
    Pb[idx] = acc * 0.125f;
  }
}

template <int S>
__global__ __launch_bounds__(256)
void attn_out(const float* __restrict__ P, const float* __restrict__ V,
              float* __restrict__ O) {
  __shared__ float Ps[25][S];
  __shared__ float Vs[S][64];
  const int h = blockIdx.x, b = blockIdx.y, t = threadIdx.x;
  const float* Pb = P + (size_t)(b * 8 + h) * 25 * S;
  for (int idx = t; idx < 25 * S; idx += 256) Ps[idx / S][idx % S] = Pb[idx];
  for (int idx = t; idx < S * 64; idx += 256) {
    int s = idx >> 6, e = idx & 63;
    Vs[s][e] = V[(b * S + s) * 512 + h * 64 + e];
  }
  __syncthreads();
  if (t < 25) {
    float mx = -1e30f;
    for (int s = 0; s < S; s++) mx = fmaxf(mx, Ps[t][s]);
    float sum = 0.f;
    for (int s = 0; s < S; s++) { float p = __expf(Ps[t][s] - mx); Ps[t][s] = p; sum += p; }
    float r = 1.f / sum;
    for (int s = 0; s < S; s++) Ps[t][s] *= r;
  }
  __syncthreads();
  for (int idx = t; idx < 25 * 64; idx += 256) {
    int l = idx >> 6, e = idx & 63;
    float acc = 0.f;
    for (int s = 0; s < S; s++) acc += Ps[l][s] * Vs[s][e];
    O[(b * 25 + l) * 512 + h * 64 + e] = acc;
  }
}

// ---------------- fused residual-add + LayerNorm (rows of 512) -----------
__global__ __launch_bounds__(128)
void add_ln(const float* __restrict__ a, const float* __restrict__ b,
            const float* __restrict__ gw, const float* __restrict__ bw,
            float* __restrict__ out) {
  const int row = blockIdx.x, t = threadIdx.x;
  float4 va = ((const float4*)(a + (size_t)row * 512))[t];
  float4 vb = ((const float4*)(b + (size_t)row * 512))[t];
  float4 v = make_float4(va.x + vb.x, va.y + vb.y, va.z + vb.z, va.w + vb.w);
  float s = v.x + v.y + v.z + v.w;
  float q = v.x * v.x + v.y * v.y + v.z * v.z + v.w * v.w;
#pragma unroll
  for (int off = 32; off > 0; off >>= 1) {
    s += __shfl_down(s, off);
    q += __shfl_down(q, off);
  }
  __shared__ float red[4];
  if ((t & 63) == 0) { red[(t >> 6) * 2] = s; red[(t >> 6) * 2 + 1] = q; }
  __syncthreads();
  float S_ = red[0] + red[2], Q_ = red[1] + red[3];
  float mean = S_ * (1.f / 512.f);
  float var  = Q_ * (1.f / 512.f) - mean * mean;
  float inv  = rsqrtf(var + EPS_LN);
  float4 g4 = ((const float4*)gw)[t];
  float4 b4 = ((const float4*)bw)[t];
  float4 o;
  o.x = (v.x - mean) * inv * g4.x + b4.x;
  o.y = (v.y - mean) * inv * g4.y + b4.y;
  o.z = (v.z - mean) * inv * g4.z + b4.z;
  o.w = (v.w - mean) * inv * g4.w + b4.w;
  ((float4*)(out + (size_t)row * 512))[t] = o;
}

// ---------------- transposes / LSTM preps --------------------------------
__global__ void transpose_dl(const float* __restrict__ in, float* __restrict__ outp) {
  const int b = blockIdx.x, t = threadIdx.x;
  for (int idx = t; idx < 25 * 512; idx += 256) {
    int l2 = idx / 512, c = idx % 512;
    outp[((size_t)b * 25 + l2) * 512 + c] = in[((size_t)b * 512 + c) * 25 + l2];
  }
}

// X0[b][t=512][32] f16 from x2[b][25][512] (u>=25 pads = 0)
__global__ __launch_bounds__(256)
void prep_x0r(const float* __restrict__ x2, _Float16* __restrict__ X0) {
  __shared__ float tile[25][516];
  const int b = blockIdx.x, t = threadIdx.x;
  for (int idx = t; idx < 25 * 512; idx += 256) {
    int u = idx >> 9, d = idx & 511;
    tile[u][d] = x2[((size_t)b * 25 + u) * 512 + d];
  }
  __syncthreads();
  for (int idx = t; idx < 512 * 32; idx += 256) {
    int d = idx >> 5, u = idx & 31;
    X0[((size_t)b * 512 + d) * 32 + u] = (u < 25) ? (_Float16)tile[u][d] : (_Float16)0.f;
  }
}

// ---------------- pipelined 32-layer LSTM (fdot2, wave-autonomous) -------
// R19 (= R18 + hardened lcons signal): 512 blocks = 8 layer-groups x 64
// pipes; block = 4 layers (one per wave) x 1 batch-pair. Intra-block
// hops via LDS SPSC ring (4 slots, ds flags); wv3->wv0 hops via the
// proven global ring protocol.
#define NLAY 32
#define LGRP 8
#define WPB  4
#define NPIPE 64
#define CHT  8
#define NCHK 64
#define NSLOT 4
#define RSLOTS 64
#define RCHK (RSLOTS / CHT)
#define RLAY ((size_t)128 * RSLOTS * 32)   // halves per layer region

__device__ __forceinline__ int ld_rlx(int* p) {
  return __hip_atomic_load(p, __ATOMIC_RELAXED, __HIP_MEMORY_SCOPE_AGENT);
}
__device__ __forceinline__ void st_rlx(int* p, int v) {
  __hip_atomic_store(p, v, __ATOMIC_RELAXED, __HIP_MEMORY_SCOPE_AGENT);
}
__device__ __forceinline__ unsigned long long ldq_rlx(const unsigned long long* p) {
  return __hip_atomic_load(p, __ATOMIC_RELAXED, __HIP_MEMORY_SCOPE_AGENT);
}
__device__ __forceinline__ void sth_rlx(_Float16* p, _Float16 v) {
  __hip_atomic_store((unsigned short*)p, __builtin_bit_cast(unsigned short, v),
                     __ATOMIC_RELAXED, __HIP_MEMORY_SCOPE_AGENT);
}
__device__ __forceinline__ int ld_lds(int* p) {
  return __hip_atomic_load(p, __ATOMIC_RELAXED, __HIP_MEMORY_SCOPE_WORKGROUP);
}
__device__ __forceinline__ void st_lds(int* p, int v) {
  __hip_atomic_store(p, v, __ATOMIC_RELAXED, __HIP_MEMORY_SCOPE_WORKGROUP);
}

__global__ __launch_bounds__(256) __attribute__((amdgpu_waves_per_eu(2, 2)))
void lstm_pipeline(const _Float16* __restrict__ X0, float* __restrict__ yout,
                   _Float16* __restrict__ ring, int* __restrict__ prod,
                   int* __restrict__ cons,
                   const float* __restrict__ Wih, const float* __restrict__ Whh,
                   const float* __restrict__ bih, const float* __restrict__ bhh) {
  const int lg = blockIdx.x / NPIPE;
  const int p  = blockIdx.x % NPIPE;
  const int t = threadIdx.x;
  const int lane = t & 63;
  const int wv = t >> 6;                 // wave = layer-in-group 0..3
  const int l  = lg * WPB + wv;          // global layer
  const int u  = lane & 31;
  const int bi = lane >> 5;              // local batch half 0..1
  const bool active = (u < 25);

  __shared__ _Float16 lbuf[3][NSLOT][CHT][2][32];  // 12 KB intra-hop rings
  __shared__ _Float16 inbuf[CHT][2][32];           // 1 KB  wv0 global stage
  __shared__ _Float16 hbuf[WPB][2][32];            // 512 B h state per wave
  __shared__ int lprod[3], lcons[3];

  // ---- init LDS (zeros keep pad lanes 25..31 at 0 forever) ----
  for (int idx = t; idx < 3 * NSLOT * CHT * 2 * 32; idx += 256)
    ((_Float16*)lbuf)[idx] = (_Float16)0.f;
  for (int idx = t; idx < CHT * 2 * 32; idx += 256)
    ((_Float16*)inbuf)[idx] = (_Float16)0.f;
  for (int idx = t; idx < WPB * 2 * 32; idx += 256)
    ((_Float16*)hbuf)[idx] = (_Float16)0.f;
  if (t < 3) { lprod[t] = 0; lcons[t] = 0; }
  __syncthreads();   // one-time init barrier

  // ---- weights packed half2: rows {u,25+u,50+u,75+u} (R5-proven) --------
  h2v wih2[4][13], whh2[4][13];
  float bias_r[4];
  float c_reg = 0.f;
  {
    const int uc = active ? u : 24;
#pragma unroll
    for (int j = 0; j < 4; j++) {
      const float* wi = &Wih[((size_t)l * 100 + j * 25 + uc) * 25];
      const float* wh = &Whh[((size_t)l * 100 + j * 25 + uc) * 25];
#pragma unroll
      for (int k = 0; k < 13; k++) {
        float alo = wi[2 * k], ahi = (2 * k + 1 < 25) ? wi[2 * k + 1] : 0.f;
        float blo = wh[2 * k], bhi = (2 * k + 1 < 25) ? wh[2 * k + 1] : 0.f;
        wih2[j][k] = h2v{(_Float16)alo, (_Float16)ahi};
        whh2[j][k] = h2v{(_Float16)blo, (_Float16)bhi};
      }
      bias_r[j] = bih[l * 100 + j * 25 + uc] + bhh[l * 100 + j * 25 + uc];
    }
  }

  // producer out pointers
  const int gb = p * 2 + bi;             // global batch of this lane's half
  _Float16* ring_out = ring + (size_t)l * RLAY + ((size_t)gb * RSLOTS) * 32 + u;
  float* yout_out = yout + ((size_t)gb * 512) * 25 + u;

  // wv0 staging map: lane -> (tc, half, 8-half segment)
  const int s_tc = lane >> 3, s_half = (lane >> 2) & 1, s_seg = lane & 3;
  const int s_gb = p * 2 + s_half;

  int* gprod_in  = prod + (lg - 1) * NPIPE + p;  // wv0 polls (lg>0)
  int* gcons_in  = cons + (lg - 1) * NPIPE + p;  // wv0 signals (lg>0)
  int* gprod_out = prod + lg * NPIPE + p;        // wv3 signals (lg<7)
  int* gcons_out = cons + lg * NPIPE + p;        // wv3 polls (lg<7)

  for (int n = 0; n < NCHK; n++) {
    const int slot = n & (NSLOT - 1);
    // ---- upstream gate ----
    if (wv == 0) {
      if (lg > 0) {
        while (ld_rlx(gprod_in) < n + 1) __builtin_amdgcn_s_sleep(1);
      }
    } else {
      while (ld_lds(&lprod[wv - 1]) < n + 1) __builtin_amdgcn_s_sleep(1);
    }
    // ---- downstream slot gate ----
    if (wv < 3) {
      if (n >= NSLOT) {
        while (ld_lds(&lcons[wv]) < n - NSLOT + 1) __builtin_amdgcn_s_sleep(1);
      }
    } else if (lg < LGRP - 1 && n >= RCHK) {
      while (ld_rlx(gcons_out) < n - RCHK + 1) __builtin_amdgcn_s_sleep(1);
    }
    asm volatile("" ::: "memory");   // no hoisting of data ops above polls

    // ---- wv0: stage global chunk into inbuf (1 x 16B per lane) ----
    if (wv == 0) {
      const int tg = n * CHT + s_tc;
      if (lg == 0) {
        const uint4* p4 = (const uint4*)(X0
            + (((size_t)s_gb * 512) + tg) * 32 + s_seg * 8);
        *(uint4*)&inbuf[s_tc][s_half][s_seg * 8] = *p4;
      } else {
        const unsigned long long* p8 = (const unsigned long long*)(ring
            + (size_t)(l - 1) * RLAY
            + (((size_t)s_gb * RSLOTS) + (tg & (RSLOTS - 1))) * 32 + s_seg * 8);
        unsigned long long a = ldq_rlx(p8);
        unsigned long long b = ldq_rlx(p8 + 1);
        *(uint4*)&inbuf[s_tc][s_half][s_seg * 8] =
            make_uint4((unsigned)a, (unsigned)(a >> 32),
                       (unsigned)b, (unsigned)(b >> 32));
      }
      asm volatile("s_waitcnt lgkmcnt(0)" ::: "memory");  // staged (wave-local)
      if (lg > 0 && lane == 0) st_rlx(gcons_in, n + 1);   // ring slot consumed
    }

    // ---- x-part for all 8 steps ----
    const _Float16* xbase = (wv == 0) ? &inbuf[0][0][0]
                                      : &lbuf[wv - 1][slot][0][0][0];
    float ax[CHT][4];
    if (active) {
#pragma unroll
      for (int tc = 0; tc < CHT; tc++) {
        const unsigned int* xr = (const unsigned int*)(xbase + (tc * 2 + bi) * 32);
        uint4 xa = *(const uint4*)(xr);
        uint4 xb = *(const uint4*)(xr + 4);
        uint4 xc = *(const uint4*)(xr + 8);
        unsigned int xd = xr[12];
        h2v xk[13] = {bch2(xa.x), bch2(xa.y), bch2(xa.z), bch2(xa.w),
                      bch2(xb.x), bch2(xb.y), bch2(xb.z), bch2(xb.w),
                      bch2(xc.x), bch2(xc.y), bch2(xc.z), bch2(xc.w),
                      bch2(xd)};
        float a0 = bias_r[0], a1 = bias_r[1], a2 = bias_r[2], a3 = bias_r[3];
#pragma unroll
        for (int k = 0; k < 13; k++) {
          a0 = fdot2(wih2[0][k], xk[k], a0);
          a1 = fdot2(wih2[1][k], xk[k], a1);
          a2 = fdot2(wih2[2][k], xk[k], a2);
          a3 = fdot2(wih2[3][k], xk[k], a3);
        }
        ax[tc][0] = a0; ax[tc][1] = a1; ax[tc][2] = a2; ax[tc][3] = a3;
      }
    }
    // free upstream LDS slot: hardened — drain our ds_reads first
    asm volatile("s_waitcnt lgkmcnt(0)" ::: "memory");
    if (wv > 0 && lane == 0) st_lds(&lcons[wv - 1], n + 1);

    // ---- serial h-recurrence: 8 steps, wave-local ----
#pragma unroll
    for (int tc = 0; tc < CHT; tc++) {
      const int tg = n * CHT + tc;
      if (active) {
        const unsigned int* hr = (const unsigned int*)&hbuf[wv][bi][0];
        uint4 ha = *(const uint4*)(hr);
        uint4 hb = *(const uint4*)(hr + 4);
        uint4 hc = *(const uint4*)(hr + 8);
        unsigned int hd = hr[12];
        h2v hk[13] = {bch2(ha.x), bch2(ha.y), bch2(ha.z), bch2(ha.w),
                      bch2(hb.x), bch2(hb.y), bch2(hb.z), bch2(hb.w),
                      bch2(hc.x), bch2(hc.y), bch2(hc.z), bch2(hc.w),
                      bch2(hd)};
        float a0 = ax[tc][0], a1 = ax[tc][1], a2 = ax[tc][2], a3 = ax[tc][3];
#pragma unroll
        for (int k = 0; k < 13; k++) {
          a0 = fdot2(whh2[0][k], hk[k], a0);
          a1 = fdot2(whh2[1][k], hk[k], a1);
          a2 = fdot2(whh2[2][k], hk[k], a2);
          a3 = fdot2(whh2[3][k], hk[k], a3);
        }
        float si = sigm_fast(a0);
        float sf = sigm_fast(a1);
        float so = sigm_fast(a3);
        c_reg = sf * c_reg + si * tanh_fast(a2);
        float h = so * tanh_fast(c_reg);
        _Float16 h16 = (_Float16)h;
        hbuf[wv][bi][u] = h16;                     // recurrence state
        if (wv < 3) {
          lbuf[wv][slot][tc][bi][u] = h16;         // intra-CU handoff
        } else if (l == NLAY - 1) {
          yout_out[(size_t)tg * 25] = h;
        } else {
          sth_rlx(ring_out + (size_t)(tg & (RSLOTS - 1)) * 32, h16);
        }
      }
    }
    // ---- publish ----
    if (wv < 3) {
      asm volatile("s_waitcnt lgkmcnt(0)" ::: "memory");
      if (lane == 0) st_lds(&lprod[wv], n + 1);
    } else {
      asm volatile("s_waitcnt vmcnt(0)" ::: "memory");   // ring stores at MALL
      if (lg < LGRP - 1 && lane == 0) st_rlx(gprod_out, n + 1);
    }
  }
}

// =====================================================================
extern "C" void kernel_launch(void* const* d_in, const int* in_sizes, int n_in,
                              void* d_out, int out_size, void* d_ws, size_t ws_size,
                              hipStream_t stream) {
  const float* x     = (const float*)d_in[0];
  const float* cross = (const float*)d_in[1];
  const float* Wq_s = (const float*)d_in[2];  const float* bq_s = (const float*)d_in[3];
  const float* Wk_s = (const float*)d_in[4];  const float* bk_s = (const float*)d_in[5];
  const float* Wv_s = (const float*)d_in[6];  const float* bv_s = (const float*)d_in[7];
  const float* Wo_s = (const float*)d_in[8];  const float* bo_s = (const float*)d_in[9];
  const float* Wq_c = (const float*)d_in[10]; const float* bq_c = (const float*)d_in[11];
  const float* Wk_c = (const float*)d_in[12]; const float* bk_c = (const float*)d_in[13];
  const float* Wv_c = (const float*)d_in[14]; const float* bv_c = (const float*)d_in[15];
  const float* Wo_c = (const float*)d_in[16]; const float* bo_c = (const float*)d_in[17];
  const float* g1 = (const float*)d_in[18]; const float* b1 = (const float*)d_in[19];
  const float* g2 = (const float*)d_in[20]; const float* b2 = (const float*)d_in[21];
  const float* g3 = (const float*)d_in[22]; const float* b3 = (const float*)d_in[23];
  const float* Wih = (const float*)d_in[24];
  const float* Whh = (const float*)d_in[25];
  const float* bih = (const float*)d_in[26];
  const float* bhh = (const float*)d_in[27];
  const float* Wc  = (const float*)d_in[28]; const float* bc = (const float*)d_in[29];
  float* out = (float*)d_out;
  float* ws  = (float*)d_ws;

  // ---- workspace (floats); time-multiplexed regions ---------------------
  constexpr size_t A  = 1638400;    // 3200*512
  constexpr size_t C6 = 6291456;    // 12288*512
  float* x1    = ws;
  float* Qc    = ws + A;
  // self phase
  float* Qs    = ws + 2 * A;
  float* Ks    = ws + 3 * A;
  float* Vs    = ws + 4 * A;
  float* attns = ws + 5 * A;
  float* tmp   = ws + 6 * A;
  float* Ps    = ws + 7 * A;
  // cross phase
  float* Kc    = ws + 2 * A;
  float* Vc    = ws + 2 * A + C6;
  float* attnc = ws + 2 * A + 2 * C6;
  float* Pc    = attnc + A;
  float* tmp2  = ws + 6 * A;
  float* x2    = ws + 3 * A;
  // lstm / post
  _Float16* X0b  = (_Float16*)(ws + 4 * A);      // 128*512*32 halves = 1.05M fl
  float*    youtb = ws + 5 * A;                  // [128][512][25] fp32
  _Float16* ringb = (_Float16*)(ws + 6 * A);     // 31*RLAY = 8.13M halves
  float* ytb   = ws + 2 * A;
  float* fy    = ws + 5 * A;                     // after youtb dead
  _Float16* WTall = (_Float16*)(ws + 20000000);
  int* ctr = (int*)(ws + 21179648);

  dim3 blk(256);
  WPtrs wpq;
  wpq.p[0] = Wq_s; wpq.p[1] = Wk_s; wpq.p[2] = Wv_s; wpq.p[3] = Wo_s;
  wpq.p[4] = Wq_c; wpq.p[5] = Wk_c; wpq.p[6] = Wv_c; wpq.p[7] = Wo_c;
  wpq.p[8] = Wc;
  prep_weights<<<dim3(16, 16, 9), blk, 0, stream>>>(wpq, WTall);
  hipMemsetAsync(ctr, 0, 4096 * sizeof(int), stream);
  _Float16* WT[9];
  for (int i = 0; i < 9; i++) WT[i] = WTall + (size_t)i * 262144;

  // ---- self attention ----
  gemm3<<<dim3(24, 50), blk, 0, stream>>>(x, WT[0], WT[1], WT[2],
                                          bq_s, bk_s, bv_s, Qs, Ks, Vs, 3200);
  attn_scores<25><<<dim3(8, 128), blk, 0, stream>>>(Qs, Ks, Ps);
  attn_out<25><<<dim3(8, 128), blk, 0, stream>>>(Ps, Vs, attns);
  gemm3<<<dim3(8, 50), blk, 0, stream>>>(attns, WT[3], WT[3], WT[3],
                                         bo_s, bo_s, bo_s, tmp, tmp, tmp, 3200);
  add_ln<<<3200, 128, 0, stream>>>(x, tmp, g1, b1, x1);
  // ---- cross attention ----
  gemm3<<<dim3(8, 50), blk, 0, stream>>>(x1, WT[4], WT[4], WT[4],
                                         bq_c, bq_c, bq_c, Qc, Qc, Qc, 3200);
  gemm3<<<dim3(16, 192), blk, 0, stream>>>(cross, WT[5], WT[6], WT[6],
                                           bk_c, bv_c, bv_c, Kc, Vc, Vc, 12288);
  attn_scores<96><<<dim3(8, 128), blk, 0, stream>>>(Qc, Kc, Pc);
  attn_out<96><<<dim3(8, 128), blk, 0, stream>>>(Pc, Vc, attnc);
  gemm3<<<dim3(8, 50), blk, 0, stream>>>(attnc, WT[7], WT[7], WT[7],
                                         bo_c, bo_c, bo_c, tmp2, tmp2, tmp2, 3200);
  add_ln<<<3200, 128, 0, stream>>>(x1, tmp2, g2, b2, x2);
  // ---- LSTM over feature axis ----
  prep_x0r<<<128, 256, 0, stream>>>(x2, X0b);
  lstm_pipeline<<<LGRP * NPIPE, 256, 0, stream>>>(X0b, youtb, ringb, ctr, ctr + 2048,
                                                  Wih, Whh, bih, bhh);
  // ---- pointwise conv over channels + final LN ----
  transpose_dl<<<128, 256, 0, stream>>>(youtb, ytb);
  gemm3<<<dim3(8, 50), blk, 0, stream>>>(ytb, WT[8], WT[8], WT[8],
                                         bc, bc, bc, fy, fy, fy, 3200);
  add_ln<<<3200, 128, 0, stream>>>(x2, fy, g3, b3, out);
}